// Round 10
// baseline (196.575 us; speedup 1.0000x reference)
//
#include <hip/hip_runtime.h>

#define EPS_LN 1e-5f

constexpr int Dm   = 768;
constexpr int Bb   = 4;
constexpr int Ls   = 1024;
constexpr int Hh   = 12;
constexpr int HD   = 64;
constexpr int ROWS = Bb * Ls;            // 4096
constexpr size_t S = (size_t)ROWS * Dm;  // 3,145,728
constexpr size_t WSZ = (size_t)Dm * Dm;  // 589,824

typedef __attribute__((ext_vector_type(8))) short bf16x8;
typedef __attribute__((ext_vector_type(4))) float f32x4;
typedef const __attribute__((address_space(1))) unsigned int* gas_p;
typedef __attribute__((address_space(3))) unsigned int* las_p;

__device__ __forceinline__ unsigned short f2bf(float f) {
  unsigned int u = __float_as_uint(f);
  u += 0x7fffu + ((u >> 16) & 1u);   // RNE
  return (unsigned short)(u >> 16);
}
__device__ __forceinline__ void gl_lds16(const unsigned short* g, unsigned short* l) {
  __builtin_amdgcn_global_load_lds((gas_p)g, (las_p)l, 16, 0, 0);
}

// =============== fused prep: 5 weight transposes + centers + LN1 (wave-per-row) ===============
__global__ void __launch_bounds__(256) prep_kernel(
    const float* __restrict__ W0, const float* __restrict__ W1,
    const float* __restrict__ W2, const float* __restrict__ W3,
    const float* __restrict__ W4, unsigned short* __restrict__ wtBase,
    const float* __restrict__ centers, const float* __restrict__ ls,
    unsigned short* __restrict__ cb, float* __restrict__ cn,
    const float* __restrict__ x, const float* __restrict__ scale,
    const float* __restrict__ shift, unsigned short* __restrict__ hb)
{
  __shared__ float smem[64 * 65];
  int bx = blockIdx.x, t = threadIdx.x;
  if (bx < 720) {
    int w = bx / 144, rem = bx - w * 144;
    int ky = rem / 12, nx = rem - ky * 12;
    const float* W = w == 0 ? W0 : w == 1 ? W1 : w == 2 ? W2 : w == 3 ? W3 : W4;
    unsigned short* WT = wtBase + (size_t)w * WSZ;
    int k0 = ky * 64, n0 = nx * 64;
    int c = t & 63, r4 = t >> 6;
    #pragma unroll
    for (int p = 0; p < 16; p++) {
      int r = p * 4 + r4;
      smem[r * 65 + c] = W[(size_t)(k0 + r) * Dm + n0 + c];
    }
    __syncthreads();
    #pragma unroll
    for (int p = 0; p < 16; p++) {
      int r = p * 4 + r4;
      WT[(size_t)(n0 + r) * Dm + k0 + c] = f2bf(smem[c * 65 + r]);
    }
  } else if (bx < 1488) {
    int j = bx - 720;
    float s = 0.f;
    #pragma unroll
    for (int i = 0; i < 3; i++) {
      int k = t + 256 * i;
      float c = centers[(size_t)j * Dm + k] / ls[k];
      cb[(size_t)j * Dm + k] = f2bf(c);
      s += c * c;
    }
    smem[t] = s; __syncthreads();
    for (int o = 128; o > 0; o >>= 1) { if (t < o) smem[t] += smem[t + o]; __syncthreads(); }
    if (t == 0) cn[j] = smem[0];
  } else {
    // LN1: wave-per-row, zero barriers
    int lane = t & 63;
    int row = (bx - 1488) * 4 + (t >> 6);
    size_t base = (size_t)row * Dm;
    float4 v[3];
    #pragma unroll
    for (int j = 0; j < 3; j++)
      v[j] = *(const float4*)&x[base + 4 * (lane + 64 * j)];
    float sum = 0.f;
    #pragma unroll
    for (int j = 0; j < 3; j++) sum += v[j].x + v[j].y + v[j].z + v[j].w;
    #pragma unroll
    for (int m = 1; m < 64; m <<= 1) sum += __shfl_xor(sum, m);
    float mean = sum * (1.0f / Dm);
    float4 d[3];
    float vs = 0.f;
    #pragma unroll
    for (int j = 0; j < 3; j++) {
      d[j].x = v[j].x - mean; d[j].y = v[j].y - mean;
      d[j].z = v[j].z - mean; d[j].w = v[j].w - mean;
      vs += d[j].x*d[j].x + d[j].y*d[j].y + d[j].z*d[j].z + d[j].w*d[j].w;
    }
    #pragma unroll
    for (int m = 1; m < 64; m <<= 1) vs += __shfl_xor(vs, m);
    float rstd = rsqrtf(vs * (1.0f / Dm) + EPS_LN);
    #pragma unroll
    for (int j = 0; j < 3; j++) {
      int c4 = 4 * (lane + 64 * j);
      float4 sc = *(const float4*)&scale[c4];
      float4 sh = *(const float4*)&shift[c4];
      ushort4 o4;
      o4.x = f2bf(sc.x * d[j].x * rstd + sh.x);
      o4.y = f2bf(sc.y * d[j].y * rstd + sh.y);
      o4.z = f2bf(sc.z * d[j].z * rstd + sh.z);
      o4.w = f2bf(sc.w * d[j].w * rstd + sh.w);
      *(ushort4*)&hb[base + c4] = o4;
    }
  }
}

// ---- LN2 + /ls: wave-per-row, zero barriers; hn[row] = sum(hv^2) ----
__global__ void __launch_bounds__(256) ln2_kernel(
    const float* __restrict__ xin, const float* __restrict__ scale,
    const float* __restrict__ shift, const float* __restrict__ ls,
    unsigned short* __restrict__ o, float* __restrict__ hn)
{
  int lane = threadIdx.x & 63;
  int row = blockIdx.x * 4 + (threadIdx.x >> 6);
  size_t base = (size_t)row * Dm;
  float4 v[3];
  #pragma unroll
  for (int j = 0; j < 3; j++)
    v[j] = *(const float4*)&xin[base + 4 * (lane + 64 * j)];
  float sum = 0.f;
  #pragma unroll
  for (int j = 0; j < 3; j++) sum += v[j].x + v[j].y + v[j].z + v[j].w;
  #pragma unroll
  for (int m = 1; m < 64; m <<= 1) sum += __shfl_xor(sum, m);
  float mean = sum * (1.0f / Dm);
  float4 d[3];
  float vs = 0.f;
  #pragma unroll
  for (int j = 0; j < 3; j++) {
    d[j].x = v[j].x - mean; d[j].y = v[j].y - mean;
    d[j].z = v[j].z - mean; d[j].w = v[j].w - mean;
    vs += d[j].x*d[j].x + d[j].y*d[j].y + d[j].z*d[j].z + d[j].w*d[j].w;
  }
  #pragma unroll
  for (int m = 1; m < 64; m <<= 1) vs += __shfl_xor(vs, m);
  float rstd = rsqrtf(vs * (1.0f / Dm) + EPS_LN);
  float hsum = 0.f;
  #pragma unroll
  for (int j = 0; j < 3; j++) {
    int c4 = 4 * (lane + 64 * j);
    float4 sc = *(const float4*)&scale[c4];
    float4 sh = *(const float4*)&shift[c4];
    float4 lv = *(const float4*)&ls[c4];
    float4 hv;
    hv.x = (sc.x * d[j].x * rstd + sh.x) / lv.x;
    hv.y = (sc.y * d[j].y * rstd + sh.y) / lv.y;
    hv.z = (sc.z * d[j].z * rstd + sh.z) / lv.z;
    hv.w = (sc.w * d[j].w * rstd + sh.w) / lv.w;
    ushort4 o4;
    o4.x = f2bf(hv.x); o4.y = f2bf(hv.y); o4.z = f2bf(hv.z); o4.w = f2bf(hv.w);
    *(ushort4*)&o[base + c4] = o4;
    hsum += hv.x*hv.x + hv.y*hv.y + hv.z*hv.z + hv.w*hv.w;
  }
  #pragma unroll
  for (int m = 1; m < 64; m <<= 1) hsum += __shfl_xor(hsum, m);
  if (lane == 0) hn[row] = hsum;
}

// =============== QKV as one 128x128-tile GEMM over [Q|K|V] B^T (N=2304) ===============
// R1-redo with the bank geometry fixed: kc-slab LDS layout [kc][128 rows][32 shorts]
// (64-B rows — identical fragment-read pattern to the proven 64^2 kernels; aggregate
// bank load = 8 dwords/bank = the wave64-b128 minimum). 576 blocks (2.25/CU).
// Each 128-col n-tile lies wholly in Q (0..5), K (6..11) or V (12..17); V quadrants
// are 64-aligned => head-aligned, transposed per-wave into vbt (R1-proven epilogue).
__global__ void __launch_bounds__(256) gemm_qkv128(
    const unsigned short* __restrict__ Abf,
    const unsigned short* __restrict__ BT,     // wqT|wkT|wvT contiguous [2304][768]
    unsigned short* __restrict__ qb,
    unsigned short* __restrict__ kb,
    unsigned short* __restrict__ vbt)
{
  __shared__ unsigned short sm[18432];   // staging: A kc-slabs [0..8191], B [8192..16383]
                                         // V-transpose scratch: 4 waves x [64][72] = 18432
  int tid = threadIdx.x;
  int m0 = blockIdx.y * 128, n0 = blockIdx.x * 128;
  int lane = tid & 63, wave = tid >> 6;
  int quad = lane >> 4, l15 = lane & 15;
  int wr = (wave >> 1) << 6, wc = (wave & 1) << 6;

  f32x4 acc[4][4];
  #pragma unroll
  for (int i = 0; i < 4; i++)
    #pragma unroll
    for (int j = 0; j < 4; j++) acc[i][j] = (f32x4){0.f, 0.f, 0.f, 0.f};

  const unsigned short* gA = Abf + (size_t)(m0 + (tid >> 2)) * Dm + ((tid & 3) << 3);
  const unsigned short* gB = BT  + (size_t)(n0 + (tid >> 2)) * Dm + ((tid & 3) << 3);

  for (int k0 = 0; k0 < Dm; k0 += 64) {
    #pragma unroll
    for (int kc = 0; kc < 2; kc++)
      #pragma unroll
      for (int h = 0; h < 2; h++) {
        gl_lds16(gA + k0 + kc * 32 + (size_t)(h * 64) * Dm, &sm[kc * 4096 + h * 2048 + tid * 8]);
        gl_lds16(gB + k0 + kc * 32 + (size_t)(h * 64) * Dm, &sm[8192 + kc * 4096 + h * 2048 + tid * 8]);
      }
    __syncthreads();
    #pragma unroll
    for (int kc = 0; kc < 2; kc++) {
      bf16x8 af[4], bfv[4];
      #pragma unroll
      for (int i = 0; i < 4; i++) {
        af[i]  = *(const bf16x8*)&sm[kc * 4096 + (wr + i * 16 + l15) * 32 + quad * 8];
        bfv[i] = *(const bf16x8*)&sm[8192 + kc * 4096 + (wc + i * 16 + l15) * 32 + quad * 8];
      }
      #pragma unroll
      for (int mi = 0; mi < 4; mi++)
        #pragma unroll
        for (int ni = 0; ni < 4; ni++)
          acc[mi][ni] = __builtin_amdgcn_mfma_f32_16x16x32_bf16(af[mi], bfv[ni], acc[mi][ni], 0, 0, 0);
    }
    __syncthreads();
  }

  if (n0 < 1536) {
    unsigned short* ob = n0 < 768 ? qb : kb;
    int nb = n0 < 768 ? n0 : n0 - 768;
    #pragma unroll
    for (int mi = 0; mi < 4; mi++)
      #pragma unroll
      for (int ni = 0; ni < 4; ni++)
        #pragma unroll
        for (int rg = 0; rg < 4; rg++) {
          int gr = m0 + wr + mi * 16 + quad * 4 + rg;
          int gc = nb + wc + ni * 16 + l15;
          ob[(size_t)gr * Dm + gc] = f2bf(acc[mi][ni][rg]);
        }
  } else {
    // V: per-wave 64x64 transpose into scratch, then cooperative store to vbt
    unsigned short* tr = sm + wave * 4608;   // [64 dims][72]
    #pragma unroll
    for (int mi = 0; mi < 4; mi++)
      #pragma unroll
      for (int ni = 0; ni < 4; ni++)
        #pragma unroll
        for (int rg = 0; rg < 4; rg++) {
          int rl = mi * 16 + quad * 4 + rg;   // key-local 0..63
          int cl = ni * 16 + l15;             // dim-local 0..63
          tr[cl * 72 + rl] = f2bf(acc[mi][ni][rg]);
        }
    __syncthreads();
    int b_ = m0 >> 10, key0 = m0 & 1023;
    int d = tid >> 2, c0 = (tid & 3) << 4;
    #pragma unroll
    for (int wq = 0; wq < 4; wq++) {
      int wrq = (wq >> 1) << 6;               // key offset of quadrant
      int wcq = (wq & 1) << 6;                // dim offset of quadrant
      int h = ((n0 - 1536) + wcq) >> 6;       // head (quadrant is 64-aligned)
      unsigned short* dst = vbt + ((size_t)((h * 4 + b_) * 64 + d)) * 1024 + key0 + wrq + c0;
      const unsigned short* srcp = &sm[wq * 4608 + d * 72 + c0];
      #pragma unroll
      for (int i = 0; i < 16; i += 4)
        *(ushort4*)(dst + i) = *(const ushort4*)(srcp + i);
    }
  }
}

// =============== MFMA bf16 GEMM, 64x64 tile, BK=64 (modes 1..3) — R0-proven ===============
template<int MODE>
__global__ void __launch_bounds__(256) gemm64(
    const unsigned short* __restrict__ Abf,
    const unsigned short* __restrict__ BT,
    unsigned short* __restrict__ o0,
    float* __restrict__ outF,
    const float* __restrict__ residF,
    const float* __restrict__ biasF,
    const float* __restrict__ hn,
    const float* __restrict__ cn)
{
  __shared__ unsigned short Asm[2][2048];
  __shared__ unsigned short Bsm[2][2048];
  int tid = threadIdx.x;
  int m0 = blockIdx.y * 64, n0 = blockIdx.x * 64;

  if (MODE >= 2) {
    __shared__ float r2[256];
    float mn = 1e30f;
    for (int i = tid; i < ROWS; i += 256) mn = fminf(mn, hn[i]);
    r2[tid] = mn; __syncthreads();
    for (int o = 128; o > 0; o >>= 1) { if (tid < o) r2[tid] = fminf(r2[tid], r2[tid + o]); __syncthreads(); }
    float hmin = r2[0];
    __syncthreads();
    float mx = 0.f;
    for (int i = tid; i < Dm; i += 256) mx = fmaxf(mx, cn[i]);
    r2[tid] = mx; __syncthreads();
    for (int o = 128; o > 0; o >>= 1) { if (tid < o) r2[tid] = fmaxf(r2[tid], r2[tid + o]); __syncthreads(); }
    float cmax = r2[0];
    float a = sqrtf(hmin), bq = sqrtf(cmax);
    bool allz = (a > bq) && ((a - bq) * (a - bq) > 300.0f);
    if (allz) {
      if (MODE == 2) return;               // Km identically 0; nobody reads it
      int r = m0 + (tid >> 2), c0 = n0 + (tid & 3) * 16;
      size_t idx = (size_t)r * Dm + c0;
      #pragma unroll
      for (int i = 0; i < 16; i += 4) {
        float4 xv = *(const float4*)(residF + idx + i);
        float4 ov;
        ov.x = xv.x + biasF[c0 + i + 0];
        ov.y = xv.y + biasF[c0 + i + 1];
        ov.z = xv.z + biasF[c0 + i + 2];
        ov.w = xv.w + biasF[c0 + i + 3];
        *(float4*)(outF + idx + i) = ov;
      }
      return;
    }
    __syncthreads();
  }

  int lane = tid & 63, wave = tid >> 6;
  int quad = lane >> 4, l15 = lane & 15;
  int wr = (wave >> 1) << 5, wc = (wave & 1) << 5;

  f32x4 acc[2][2];
  #pragma unroll
  for (int i = 0; i < 2; i++)
    #pragma unroll
    for (int j = 0; j < 2; j++) acc[i][j] = (f32x4){0.f, 0.f, 0.f, 0.f};

  const unsigned short* gA = Abf + (size_t)(m0 + (tid >> 2)) * Dm + ((tid & 3) << 3);
  const unsigned short* gB = BT  + (size_t)(n0 + (tid >> 2)) * Dm + ((tid & 3) << 3);

  union Frag { bf16x8 v; ushort4 h[2]; };

  for (int k0 = 0; k0 < Dm; k0 += 64) {
    gl_lds16(gA + k0,      &Asm[0][tid * 8]);
    gl_lds16(gA + k0 + 32, &Asm[1][tid * 8]);
    gl_lds16(gB + k0,      &Bsm[0][tid * 8]);
    gl_lds16(gB + k0 + 32, &Bsm[1][tid * 8]);
    __syncthreads();
    #pragma unroll
    for (int kc = 0; kc < 2; kc++) {
      Frag af[2], bfb[2];
      #pragma unroll
      for (int i = 0; i < 2; i++) {
        af[i].v  = *(const bf16x8*)&Asm[kc][(wr + i * 16 + l15) * 32 + quad * 8];
        bfb[i].v = *(const bf16x8*)&Bsm[kc][(wc + i * 16 + l15) * 32 + quad * 8];
      }
      #pragma unroll
      for (int mi = 0; mi < 2; mi++)
        #pragma unroll
        for (int ni = 0; ni < 2; ni++)
          acc[mi][ni] = __builtin_amdgcn_mfma_f32_16x16x32_bf16(
              af[mi].v, bfb[ni].v, acc[mi][ni], 0, 0, 0);
    }
    __syncthreads();
  }

  #pragma unroll
  for (int mi = 0; mi < 2; mi++)
    #pragma unroll
    for (int ni = 0; ni < 2; ni++)
      #pragma unroll
      for (int rg = 0; rg < 4; rg++) {
        int gr = m0 + wr + mi * 16 + quad * 4 + rg;
        int gc = n0 + wc + ni * 16 + l15;
        size_t idx = (size_t)gr * Dm + gc;
        float v = acc[mi][ni][rg];
        if (MODE == 2) {
          float sq = fmaxf(hn[gr] + cn[gc] - 2.0f * v, 0.f);
          o0[idx] = f2bf(__expf(-0.5f * sq));
        } else {
          outF[idx] = residF[idx] + v + biasF[gc];
        }
      }
}

// =============== flash attention v6 (R9): 2-phase prefetch, double-buffered K/V ===============
__global__ void __launch_bounds__(256) attn_flash(
    const unsigned short* __restrict__ q,
    const unsigned short* __restrict__ k,
    const unsigned short* __restrict__ vbt,
    unsigned short* __restrict__ ctx)
{
  int bx = blockIdx.x;
  int qt = (bx & 1) ? (15 - (bx >> 1)) : (bx >> 1);
  int h  = blockIdx.y;
  int b  = blockIdx.z;
  int tid = threadIdx.x;
  int lane = tid & 63, wave = tid >> 6;
  int quad = lane >> 4, l15 = lane & 15;

  __shared__ unsigned short Ks[2][2][2048];   // [buf][kc]
  __shared__ unsigned short Vt[2][2][2048];
  __shared__ unsigned short QP[4608];

  size_t baseQK = (size_t)(b * Ls) * Dm + h * HD;
  const unsigned short* gVt = vbt + (size_t)((h * 4 + b) * 64 + (tid >> 2)) * 1024 + ((tid & 3) << 3);

  {
    const unsigned short* gQ = q + baseQK + (size_t)(qt * 64 + (tid >> 2)) * Dm + ((tid & 3) << 3);
    gl_lds16(gQ,      &QP[tid * 8]);
    gl_lds16(gQ + 32, &QP[2048 + tid * 8]);
  }
  __syncthreads();

  union Frag { bf16x8 v; ushort4 h[2]; };
  Frag afq[2];
  #pragma unroll
  for (int kc = 0; kc < 2; kc++)
    afq[kc].v = *(const bf16x8*)&QP[kc * 2048 + (wave * 16 + l15) * 32 + quad * 8];
  asm volatile("s_waitcnt lgkmcnt(0)" ::: "memory");

  f32x4 O[4];
  #pragma unroll
  for (int nj = 0; nj < 4; nj++) O[nj] = (f32x4){0.f, 0.f, 0.f, 0.f};
  float lsum[4] = {0.f, 0.f, 0.f, 0.f};

  const unsigned short* gK = k + baseQK + (size_t)(tid >> 2) * Dm + ((tid & 3) << 3);

  gl_lds16(gK,      &Ks[0][0][tid * 8]);
  gl_lds16(gK + 32, &Ks[0][1][tid * 8]);
  gl_lds16(gVt,      &Vt[0][0][tid * 8]);
  gl_lds16(gVt + 32, &Vt[0][1][tid * 8]);

  for (int kt = 0; kt <= qt; kt++) {
    int cur = kt & 1;
    asm volatile("s_waitcnt lgkmcnt(0)" ::: "memory");
    __builtin_amdgcn_s_barrier();
    if (kt < qt) {
      int nxt = cur ^ 1;
      gl_lds16(gK + (size_t)((kt + 1) * 64) * Dm,      &Ks[nxt][0][tid * 8]);
      gl_lds16(gK + (size_t)((kt + 1) * 64) * Dm + 32, &Ks[nxt][1][tid * 8]);
      gl_lds16(gVt + (kt + 1) * 64,      &Vt[nxt][0][tid * 8]);
      gl_lds16(gVt + (kt + 1) * 64 + 32, &Vt[nxt][1][tid * 8]);
      asm volatile("s_waitcnt vmcnt(4)" ::: "memory");
    } else {
      asm volatile("s_waitcnt vmcnt(0)" ::: "memory");
    }
    __builtin_amdgcn_s_barrier();
    __builtin_amdgcn_sched_barrier(0);

    f32x4 sacc[4];
    #pragma unroll
    for (int ni = 0; ni < 4; ni++) {
      sacc[ni] = (f32x4){0.f, 0.f, 0.f, 0.f};
      #pragma unroll
      for (int kc = 0; kc < 2; kc++) {
        Frag bk;
        bk.v = *(const bf16x8*)&Ks[cur][kc][(ni * 16 + l15) * 32 + quad * 8];
        sacc[ni] = __builtin_amdgcn_mfma_f32_16x16x32_bf16(afq[kc].v, bk.v, sacc[ni], 0, 0, 0);
      }
    }

    if (kt == qt) {
      #pragma unroll
      for (int ni = 0; ni < 4; ni++)
        #pragma unroll
        for (int rg = 0; rg < 4; rg++) {
          int rowl = wave * 16 + quad * 4 + rg;
          int coll = ni * 16 + l15;
          if (coll > rowl) sacc[ni][rg] = -1e30f;
        }
    }

    unsigned short (*Ps)[72] = (unsigned short(*)[72])QP;
    #pragma unroll
    for (int ni = 0; ni < 4; ni++)
      #pragma unroll
      for (int rg = 0; rg < 4; rg++) {
        float p = __expf(sacc[ni][rg] * 0.125f);
        lsum[rg] += p;
        Ps[wave * 16 + quad * 4 + rg][ni * 16 + l15] = f2bf(p);
      }

    Frag ap[2];
    #pragma unroll
    for (int kc = 0; kc < 2; kc++)
      ap[kc].v = *(const bf16x8*)&Ps[wave * 16 + l15][kc * 32 + quad * 8];

    #pragma unroll
    for (int nj = 0; nj < 4; nj++)
      #pragma unroll
      for (int kc = 0; kc < 2; kc++) {
        Frag bv;
        bv.v = *(const bf16x8*)&Vt[cur][kc][(nj * 16 + l15) * 32 + quad * 8];
        O[nj] = __builtin_amdgcn_mfma_f32_16x16x32_bf16(ap[kc].v, bv.v, O[nj], 0, 0, 0);
      }
  }

  float linv[4];
  #pragma unroll
  for (int rg = 0; rg < 4; rg++) {
    float l = lsum[rg];
    #pragma unroll
    for (int m = 1; m < 16; m <<= 1) l += __shfl_xor(l, m, 16);
    linv[rg] = 1.0f / l;
  }
  #pragma unroll
  for (int nj = 0; nj < 4; nj++)
    #pragma unroll
    for (int rg = 0; rg < 4; rg++) {
      int row = qt * 64 + wave * 16 + quad * 4 + rg;
      int col = nj * 16 + l15;
      ctx[baseQK + (size_t)row * Dm + col] = f2bf(O[nj][rg] * linv[rg]);
    }
}

extern "C" void kernel_launch(void* const* d_in, const int* in_sizes, int n_in,
                              void* d_out, int out_size, void* d_ws, size_t ws_size,
                              hipStream_t stream)
{
  const float* x      = (const float*)d_in[0];
  const float* Wq     = (const float*)d_in[1];
  const float* Wk     = (const float*)d_in[2];
  const float* Wv     = (const float*)d_in[3];
  const float* Wo     = (const float*)d_in[4];
  const float* bo     = (const float*)d_in[5];
  const float* scale1 = (const float*)d_in[6];
  const float* shift1 = (const float*)d_in[7];
  const float* scale2 = (const float*)d_in[8];
  const float* shift2 = (const float*)d_in[9];
  const float* centers= (const float*)d_in[10];
  const float* lsp    = (const float*)d_in[11];
  const float* Wf     = (const float*)d_in[12];
  const float* bfv    = (const float*)d_in[13];
  float* out = (float*)d_out;

  unsigned short* wsu = (unsigned short*)d_ws;
  unsigned short* wqT = wsu;                 // [768][768]  \
  unsigned short* wkT = wsu + WSZ;           // [768][768]   } contiguous 2304x768 B^T
  unsigned short* wvT = wsu + 2 * WSZ;       // [768][768]  /
  unsigned short* woT = wsu + 3 * WSZ;
  unsigned short* wfT = wsu + 4 * WSZ;
  unsigned short* cb  = wsu + 5 * WSZ;
  unsigned short* bufA = wsu + 6 * WSZ;
  unsigned short* bufB = bufA + S;
  unsigned short* hb  = bufA;
  unsigned short* qb  = bufB;
  unsigned short* kb  = bufB + S;
  unsigned short* vbt = bufB + 2 * S;
  unsigned short* ctx = bufA;
  float* x1f          = (float*)bufB;
  unsigned short* hf  = bufB + 2 * S;
  unsigned short* Km  = bufA;
  float* hn = (float*)(bufB + 3 * S);
  float* cn = hn + ROWS;

  dim3 gg(Dm / 64, ROWS / 64);         // (12, 64)

  prep_kernel<<<2512, 256, 0, stream>>>(Wq, Wk, Wv, Wo, Wf, wsu,
                                        centers, lsp, cb, cn,
                                        x, scale1, shift1, hb);
  gemm_qkv128<<<dim3(18, 32), 256, 0, stream>>>(hb, wqT, qb, kb, vbt);
  attn_flash<<<dim3(Ls / 64, Hh, Bb), 256, 0, stream>>>(qb, kb, vbt, ctx);
  gemm64<1><<<gg, 256, 0, stream>>>(ctx, woT, nullptr, x1f, x, bo, nullptr, nullptr);
  ln2_kernel<<<ROWS / 4, 256, 0, stream>>>(x1f, scale2, shift2, lsp, hf, hn);
  gemm64<2><<<gg, 256, 0, stream>>>(hf, cb, Km, nullptr, nullptr, nullptr, hn, cn);
  gemm64<3><<<gg, 256, 0, stream>>>(Km, wfT, nullptr, out, x1f, bfv, hn, cn);
}

// Round 11
// 182.890 us; speedup vs baseline: 1.0748x; 1.0748x over previous
//
#include <hip/hip_runtime.h>

#define EPS_LN 1e-5f

constexpr int Dm   = 768;
constexpr int Bb   = 4;
constexpr int Ls   = 1024;
constexpr int Hh   = 12;
constexpr int HD   = 64;
constexpr int ROWS = Bb * Ls;            // 4096
constexpr size_t S = (size_t)ROWS * Dm;  // 3,145,728
constexpr size_t WSZ = (size_t)Dm * Dm;  // 589,824

typedef __attribute__((ext_vector_type(8))) short bf16x8;
typedef __attribute__((ext_vector_type(4))) float f32x4;
typedef const __attribute__((address_space(1))) unsigned int* gas_p;
typedef __attribute__((address_space(3))) unsigned int* las_p;

__device__ __forceinline__ unsigned short f2bf(float f) {
  unsigned int u = __float_as_uint(f);
  u += 0x7fffu + ((u >> 16) & 1u);   // RNE
  return (unsigned short)(u >> 16);
}
__device__ __forceinline__ void gl_lds16(const unsigned short* g, unsigned short* l) {
  __builtin_amdgcn_global_load_lds((gas_p)g, (las_p)l, 16, 0, 0);
}

// =============== fused prep: 5 weight transposes + centers + LN1 (wave-per-row) ===============
__global__ void __launch_bounds__(256) prep_kernel(
    const float* __restrict__ W0, const float* __restrict__ W1,
    const float* __restrict__ W2, const float* __restrict__ W3,
    const float* __restrict__ W4, unsigned short* __restrict__ wtBase,
    const float* __restrict__ centers, const float* __restrict__ ls,
    unsigned short* __restrict__ cb, float* __restrict__ cn,
    const float* __restrict__ x, const float* __restrict__ scale,
    const float* __restrict__ shift, unsigned short* __restrict__ hb)
{
  __shared__ float smem[64 * 65];
  int bx = blockIdx.x, t = threadIdx.x;
  if (bx < 720) {
    int w = bx / 144, rem = bx - w * 144;
    int ky = rem / 12, nx = rem - ky * 12;
    const float* W = w == 0 ? W0 : w == 1 ? W1 : w == 2 ? W2 : w == 3 ? W3 : W4;
    unsigned short* WT = wtBase + (size_t)w * WSZ;
    int k0 = ky * 64, n0 = nx * 64;
    int c = t & 63, r4 = t >> 6;
    #pragma unroll
    for (int p = 0; p < 16; p++) {
      int r = p * 4 + r4;
      smem[r * 65 + c] = W[(size_t)(k0 + r) * Dm + n0 + c];
    }
    __syncthreads();
    #pragma unroll
    for (int p = 0; p < 16; p++) {
      int r = p * 4 + r4;
      WT[(size_t)(n0 + r) * Dm + k0 + c] = f2bf(smem[c * 65 + r]);
    }
  } else if (bx < 1488) {
    int j = bx - 720;
    float s = 0.f;
    #pragma unroll
    for (int i = 0; i < 3; i++) {
      int k = t + 256 * i;
      float c = centers[(size_t)j * Dm + k] / ls[k];
      cb[(size_t)j * Dm + k] = f2bf(c);
      s += c * c;
    }
    smem[t] = s; __syncthreads();
    for (int o = 128; o > 0; o >>= 1) { if (t < o) smem[t] += smem[t + o]; __syncthreads(); }
    if (t == 0) cn[j] = smem[0];
  } else {
    // LN1: wave-per-row, zero barriers
    int lane = t & 63;
    int row = (bx - 1488) * 4 + (t >> 6);
    size_t base = (size_t)row * Dm;
    float4 v[3];
    #pragma unroll
    for (int j = 0; j < 3; j++)
      v[j] = *(const float4*)&x[base + 4 * (lane + 64 * j)];
    float sum = 0.f;
    #pragma unroll
    for (int j = 0; j < 3; j++) sum += v[j].x + v[j].y + v[j].z + v[j].w;
    #pragma unroll
    for (int m = 1; m < 64; m <<= 1) sum += __shfl_xor(sum, m);
    float mean = sum * (1.0f / Dm);
    float4 d[3];
    float vs = 0.f;
    #pragma unroll
    for (int j = 0; j < 3; j++) {
      d[j].x = v[j].x - mean; d[j].y = v[j].y - mean;
      d[j].z = v[j].z - mean; d[j].w = v[j].w - mean;
      vs += d[j].x*d[j].x + d[j].y*d[j].y + d[j].z*d[j].z + d[j].w*d[j].w;
    }
    #pragma unroll
    for (int m = 1; m < 64; m <<= 1) vs += __shfl_xor(vs, m);
    float rstd = rsqrtf(vs * (1.0f / Dm) + EPS_LN);
    #pragma unroll
    for (int j = 0; j < 3; j++) {
      int c4 = 4 * (lane + 64 * j);
      float4 sc = *(const float4*)&scale[c4];
      float4 sh = *(const float4*)&shift[c4];
      ushort4 o4;
      o4.x = f2bf(sc.x * d[j].x * rstd + sh.x);
      o4.y = f2bf(sc.y * d[j].y * rstd + sh.y);
      o4.z = f2bf(sc.z * d[j].z * rstd + sh.z);
      o4.w = f2bf(sc.w * d[j].w * rstd + sh.w);
      *(ushort4*)&hb[base + c4] = o4;
    }
  }
}

// ---- LN2 + /ls: wave-per-row, zero barriers; hn[row] = sum(hv^2) ----
__global__ void __launch_bounds__(256) ln2_kernel(
    const float* __restrict__ xin, const float* __restrict__ scale,
    const float* __restrict__ shift, const float* __restrict__ ls,
    unsigned short* __restrict__ o, float* __restrict__ hn)
{
  int lane = threadIdx.x & 63;
  int row = blockIdx.x * 4 + (threadIdx.x >> 6);
  size_t base = (size_t)row * Dm;
  float4 v[3];
  #pragma unroll
  for (int j = 0; j < 3; j++)
    v[j] = *(const float4*)&xin[base + 4 * (lane + 64 * j)];
  float sum = 0.f;
  #pragma unroll
  for (int j = 0; j < 3; j++) sum += v[j].x + v[j].y + v[j].z + v[j].w;
  #pragma unroll
  for (int m = 1; m < 64; m <<= 1) sum += __shfl_xor(sum, m);
  float mean = sum * (1.0f / Dm);
  float4 d[3];
  float vs = 0.f;
  #pragma unroll
  for (int j = 0; j < 3; j++) {
    d[j].x = v[j].x - mean; d[j].y = v[j].y - mean;
    d[j].z = v[j].z - mean; d[j].w = v[j].w - mean;
    vs += d[j].x*d[j].x + d[j].y*d[j].y + d[j].z*d[j].z + d[j].w*d[j].w;
  }
  #pragma unroll
  for (int m = 1; m < 64; m <<= 1) vs += __shfl_xor(vs, m);
  float rstd = rsqrtf(vs * (1.0f / Dm) + EPS_LN);
  float hsum = 0.f;
  #pragma unroll
  for (int j = 0; j < 3; j++) {
    int c4 = 4 * (lane + 64 * j);
    float4 sc = *(const float4*)&scale[c4];
    float4 sh = *(const float4*)&shift[c4];
    float4 lv = *(const float4*)&ls[c4];
    float4 hv;
    hv.x = (sc.x * d[j].x * rstd + sh.x) / lv.x;
    hv.y = (sc.y * d[j].y * rstd + sh.y) / lv.y;
    hv.z = (sc.z * d[j].z * rstd + sh.z) / lv.z;
    hv.w = (sc.w * d[j].w * rstd + sh.w) / lv.w;
    ushort4 o4;
    o4.x = f2bf(hv.x); o4.y = f2bf(hv.y); o4.z = f2bf(hv.z); o4.w = f2bf(hv.w);
    *(ushort4*)&o[base + c4] = o4;
    hsum += hv.x*hv.x + hv.y*hv.y + hv.z*hv.z + hv.w*hv.w;
  }
  #pragma unroll
  for (int m = 1; m < 64; m <<= 1) hsum += __shfl_xor(hsum, m);
  if (lane == 0) hn[row] = hsum;
}

// ---- 1-block reduce: flags[0]=min(hn), flags[1]=max(cn). min/max are order-independent,
// so the degeneracy DECISION is bit-identical to the old per-block scans. Replaces the
// 19KB scan + 16-barrier trees previously run in all 1536 gemm64<2,3> blocks.
__global__ void __launch_bounds__(256) reduce_flags(
    const float* __restrict__ hn, const float* __restrict__ cn,
    float* __restrict__ flags)
{
  __shared__ float r2[256];
  int t = threadIdx.x;
  float mn = 1e30f;
  for (int i = t; i < ROWS; i += 256) mn = fminf(mn, hn[i]);
  r2[t] = mn; __syncthreads();
  for (int o = 128; o > 0; o >>= 1) { if (t < o) r2[t] = fminf(r2[t], r2[t + o]); __syncthreads(); }
  if (t == 0) flags[0] = r2[0];
  __syncthreads();
  float mx = 0.f;
  for (int i = t; i < Dm; i += 256) mx = fmaxf(mx, cn[i]);
  r2[t] = mx; __syncthreads();
  for (int o = 128; o > 0; o >>= 1) { if (t < o) r2[t] = fmaxf(r2[t], r2[t + o]); __syncthreads(); }
  if (t == 0) flags[1] = r2[0];
}

// =============== QKV 3-in-1 GEMM (R0-proven; 128^2 variant refuted twice) ===============
__global__ void __launch_bounds__(256) gemm_qkv(
    const unsigned short* __restrict__ Abf,
    const unsigned short* __restrict__ wqT,
    const unsigned short* __restrict__ wkT,
    const unsigned short* __restrict__ wvT,
    unsigned short* __restrict__ qb,
    unsigned short* __restrict__ kb,
    unsigned short* __restrict__ vbt)
{
  int m0 = blockIdx.y * 64, n0 = blockIdx.x * 64;
  __shared__ unsigned short sm[4096 + 3 * 4096];
  int tid = threadIdx.x;
  int lane = tid & 63, wave = tid >> 6;
  int quad = lane >> 4, l15 = lane & 15;
  int wr = (wave >> 1) << 5, wc = (wave & 1) << 5;

  f32x4 acc[3][2][2];
  #pragma unroll
  for (int w = 0; w < 3; w++)
    #pragma unroll
    for (int i = 0; i < 2; i++)
      #pragma unroll
      for (int j = 0; j < 2; j++) acc[w][i][j] = (f32x4){0.f, 0.f, 0.f, 0.f};

  const unsigned short* gA = Abf + (size_t)(m0 + (tid >> 2)) * Dm + ((tid & 3) << 3);
  size_t bOff = (size_t)(n0 + (tid >> 2)) * Dm + ((tid & 3) << 3);
  const unsigned short* gB[3] = { wqT + bOff, wkT + bOff, wvT + bOff };

  union Frag { bf16x8 v; ushort4 h[2]; };

  for (int k0 = 0; k0 < Dm; k0 += 64) {
    gl_lds16(gA + k0,      &sm[tid * 8]);
    gl_lds16(gA + k0 + 32, &sm[2048 + tid * 8]);
    #pragma unroll
    for (int w = 0; w < 3; w++) {
      gl_lds16(gB[w] + k0,      &sm[4096 + w * 4096 + tid * 8]);
      gl_lds16(gB[w] + k0 + 32, &sm[4096 + w * 4096 + 2048 + tid * 8]);
    }
    __syncthreads();
    Frag af[2][2];
    #pragma unroll
    for (int kc = 0; kc < 2; kc++)
      #pragma unroll
      for (int mi = 0; mi < 2; mi++)
        af[kc][mi].v = *(const bf16x8*)&sm[kc * 2048 + (wr + mi * 16 + l15) * 32 + quad * 8];
    #pragma unroll
    for (int w = 0; w < 3; w++)
      #pragma unroll
      for (int kc = 0; kc < 2; kc++)
        #pragma unroll
        for (int ni = 0; ni < 2; ni++) {
          Frag bf;
          bf.v = *(const bf16x8*)&sm[4096 + w * 4096 + kc * 2048 + (wc + ni * 16 + l15) * 32 + quad * 8];
          #pragma unroll
          for (int mi = 0; mi < 2; mi++)
            acc[w][mi][ni] = __builtin_amdgcn_mfma_f32_16x16x32_bf16(
                af[kc][mi].v, bf.v, acc[w][mi][ni], 0, 0, 0);
        }
    __syncthreads();
  }

  #pragma unroll
  for (int w = 0; w < 2; w++) {
    unsigned short* ob = w ? kb : qb;
    #pragma unroll
    for (int mi = 0; mi < 2; mi++)
      #pragma unroll
      for (int ni = 0; ni < 2; ni++)
        #pragma unroll
        for (int rg = 0; rg < 4; rg++) {
          int gr = m0 + wr + mi * 16 + quad * 4 + rg;
          int gc = n0 + wc + ni * 16 + l15;
          ob[(size_t)gr * Dm + gc] = f2bf(acc[w][mi][ni][rg]);
        }
  }
  #pragma unroll
  for (int mi = 0; mi < 2; mi++)
    #pragma unroll
    for (int ni = 0; ni < 2; ni++)
      #pragma unroll
      for (int rg = 0; rg < 4; rg++) {
        int rl = wr + mi * 16 + quad * 4 + rg;
        int cl = wc + ni * 16 + l15;
        sm[cl * 72 + rl] = f2bf(acc[2][mi][ni][rg]);
      }
  __syncthreads();
  {
    int d = tid >> 2, c0 = (tid & 3) * 16;
    int b_ = m0 >> 10, keybase = m0 & 1023;
    unsigned short* dst = vbt + ((size_t)((blockIdx.x * 4 + b_) * 64 + d)) * 1024 + keybase + c0;
    #pragma unroll
    for (int i = 0; i < 16; i += 4)
      *(ushort4*)(dst + i) = *(const ushort4*)&sm[d * 72 + c0 + i];
  }
}

// =============== MFMA bf16 GEMM, 64x64 tile, BK=64 (modes 1..3) ===============
// MODE>=2 degeneracy decision now reads flags[0]=min(hn), flags[1]=max(cn) computed
// once by reduce_flags (order-independent min/max -> identical decision).
// Degeneracy proof: sq >= (sqrt(hn)-sqrt(cn))^2 (Cauchy-Schwarz, minus <=2.5 bf16 slack);
// fp32 exp(-x)==0.0 exactly for x>=104 i.e. sq>=208. Threshold 300 adds margin.
template<int MODE>
__global__ void __launch_bounds__(256) gemm64(
    const unsigned short* __restrict__ Abf,
    const unsigned short* __restrict__ BT,
    unsigned short* __restrict__ o0,
    float* __restrict__ outF,
    const float* __restrict__ residF,
    const float* __restrict__ biasF,
    const float* __restrict__ hn,
    const float* __restrict__ cn,
    const float* __restrict__ flags)
{
  __shared__ unsigned short Asm[2][2048];
  __shared__ unsigned short Bsm[2][2048];
  int tid = threadIdx.x;
  int m0 = blockIdx.y * 64, n0 = blockIdx.x * 64;

  if (MODE >= 2) {
    float hmin = flags[0];
    float cmax = flags[1];
    float a = sqrtf(hmin), bq = sqrtf(cmax);
    bool allz = (a > bq) && ((a - bq) * (a - bq) > 300.0f);
    if (allz) {
      if (MODE == 2) return;               // Km identically 0; nobody reads it
      // MODE 3: out = x1 + bias, elementwise over this tile
      int r = m0 + (tid >> 2), c0 = n0 + (tid & 3) * 16;
      size_t idx = (size_t)r * Dm + c0;
      #pragma unroll
      for (int i = 0; i < 16; i += 4) {
        float4 xv = *(const float4*)(residF + idx + i);
        float4 ov;
        ov.x = xv.x + biasF[c0 + i + 0];
        ov.y = xv.y + biasF[c0 + i + 1];
        ov.z = xv.z + biasF[c0 + i + 2];
        ov.w = xv.w + biasF[c0 + i + 3];
        *(float4*)(outF + idx + i) = ov;
      }
      return;
    }
  }

  int lane = tid & 63, wave = tid >> 6;
  int quad = lane >> 4, l15 = lane & 15;
  int wr = (wave >> 1) << 5, wc = (wave & 1) << 5;

  f32x4 acc[2][2];
  #pragma unroll
  for (int i = 0; i < 2; i++)
    #pragma unroll
    for (int j = 0; j < 2; j++) acc[i][j] = (f32x4){0.f, 0.f, 0.f, 0.f};

  const unsigned short* gA = Abf + (size_t)(m0 + (tid >> 2)) * Dm + ((tid & 3) << 3);
  const unsigned short* gB = BT  + (size_t)(n0 + (tid >> 2)) * Dm + ((tid & 3) << 3);

  union Frag { bf16x8 v; ushort4 h[2]; };

  for (int k0 = 0; k0 < Dm; k0 += 64) {
    gl_lds16(gA + k0,      &Asm[0][tid * 8]);
    gl_lds16(gA + k0 + 32, &Asm[1][tid * 8]);
    gl_lds16(gB + k0,      &Bsm[0][tid * 8]);
    gl_lds16(gB + k0 + 32, &Bsm[1][tid * 8]);
    __syncthreads();
    #pragma unroll
    for (int kc = 0; kc < 2; kc++) {
      Frag af[2], bfb[2];
      #pragma unroll
      for (int i = 0; i < 2; i++) {
        af[i].v  = *(const bf16x8*)&Asm[kc][(wr + i * 16 + l15) * 32 + quad * 8];
        bfb[i].v = *(const bf16x8*)&Bsm[kc][(wc + i * 16 + l15) * 32 + quad * 8];
      }
      #pragma unroll
      for (int mi = 0; mi < 2; mi++)
        #pragma unroll
        for (int ni = 0; ni < 2; ni++)
          acc[mi][ni] = __builtin_amdgcn_mfma_f32_16x16x32_bf16(
              af[mi].v, bfb[ni].v, acc[mi][ni], 0, 0, 0);
    }
    __syncthreads();
  }

  #pragma unroll
  for (int mi = 0; mi < 2; mi++)
    #pragma unroll
    for (int ni = 0; ni < 2; ni++)
      #pragma unroll
      for (int rg = 0; rg < 4; rg++) {
        int gr = m0 + wr + mi * 16 + quad * 4 + rg;
        int gc = n0 + wc + ni * 16 + l15;
        size_t idx = (size_t)gr * Dm + gc;
        float v = acc[mi][ni][rg];
        if (MODE == 2) {
          float sq = fmaxf(hn[gr] + cn[gc] - 2.0f * v, 0.f);
          o0[idx] = f2bf(__expf(-0.5f * sq));
        } else {
          outF[idx] = residF[idx] + v + biasF[gc];
        }
      }
}

// =============== flash attention v6 (R9): 2-phase prefetch, double-buffered K/V ===============
__global__ void __launch_bounds__(256) attn_flash(
    const unsigned short* __restrict__ q,
    const unsigned short* __restrict__ k,
    const unsigned short* __restrict__ vbt,
    unsigned short* __restrict__ ctx)
{
  int bx = blockIdx.x;
  int qt = (bx & 1) ? (15 - (bx >> 1)) : (bx >> 1);
  int h  = blockIdx.y;
  int b  = blockIdx.z;
  int tid = threadIdx.x;
  int lane = tid & 63, wave = tid >> 6;
  int quad = lane >> 4, l15 = lane & 15;

  __shared__ unsigned short Ks[2][2][2048];   // [buf][kc]
  __shared__ unsigned short Vt[2][2][2048];
  __shared__ unsigned short QP[4608];

  size_t baseQK = (size_t)(b * Ls) * Dm + h * HD;
  const unsigned short* gVt = vbt + (size_t)((h * 4 + b) * 64 + (tid >> 2)) * 1024 + ((tid & 3) << 3);

  {
    const unsigned short* gQ = q + baseQK + (size_t)(qt * 64 + (tid >> 2)) * Dm + ((tid & 3) << 3);
    gl_lds16(gQ,      &QP[tid * 8]);
    gl_lds16(gQ + 32, &QP[2048 + tid * 8]);
  }
  __syncthreads();

  union Frag { bf16x8 v; ushort4 h[2]; };
  Frag afq[2];
  #pragma unroll
  for (int kc = 0; kc < 2; kc++)
    afq[kc].v = *(const bf16x8*)&QP[kc * 2048 + (wave * 16 + l15) * 32 + quad * 8];
  asm volatile("s_waitcnt lgkmcnt(0)" ::: "memory");

  f32x4 O[4];
  #pragma unroll
  for (int nj = 0; nj < 4; nj++) O[nj] = (f32x4){0.f, 0.f, 0.f, 0.f};
  float lsum[4] = {0.f, 0.f, 0.f, 0.f};

  const unsigned short* gK = k + baseQK + (size_t)(tid >> 2) * Dm + ((tid & 3) << 3);

  gl_lds16(gK,      &Ks[0][0][tid * 8]);
  gl_lds16(gK + 32, &Ks[0][1][tid * 8]);
  gl_lds16(gVt,      &Vt[0][0][tid * 8]);
  gl_lds16(gVt + 32, &Vt[0][1][tid * 8]);

  for (int kt = 0; kt <= qt; kt++) {
    int cur = kt & 1;
    asm volatile("s_waitcnt lgkmcnt(0)" ::: "memory");
    __builtin_amdgcn_s_barrier();
    if (kt < qt) {
      int nxt = cur ^ 1;
      gl_lds16(gK + (size_t)((kt + 1) * 64) * Dm,      &Ks[nxt][0][tid * 8]);
      gl_lds16(gK + (size_t)((kt + 1) * 64) * Dm + 32, &Ks[nxt][1][tid * 8]);
      gl_lds16(gVt + (kt + 1) * 64,      &Vt[nxt][0][tid * 8]);
      gl_lds16(gVt + (kt + 1) * 64 + 32, &Vt[nxt][1][tid * 8]);
      asm volatile("s_waitcnt vmcnt(4)" ::: "memory");
    } else {
      asm volatile("s_waitcnt vmcnt(0)" ::: "memory");
    }
    __builtin_amdgcn_s_barrier();
    __builtin_amdgcn_sched_barrier(0);

    f32x4 sacc[4];
    #pragma unroll
    for (int ni = 0; ni < 4; ni++) {
      sacc[ni] = (f32x4){0.f, 0.f, 0.f, 0.f};
      #pragma unroll
      for (int kc = 0; kc < 2; kc++) {
        Frag bk;
        bk.v = *(const bf16x8*)&Ks[cur][kc][(ni * 16 + l15) * 32 + quad * 8];
        sacc[ni] = __builtin_amdgcn_mfma_f32_16x16x32_bf16(afq[kc].v, bk.v, sacc[ni], 0, 0, 0);
      }
    }

    if (kt == qt) {
      #pragma unroll
      for (int ni = 0; ni < 4; ni++)
        #pragma unroll
        for (int rg = 0; rg < 4; rg++) {
          int rowl = wave * 16 + quad * 4 + rg;
          int coll = ni * 16 + l15;
          if (coll > rowl) sacc[ni][rg] = -1e30f;
        }
    }

    unsigned short (*Ps)[72] = (unsigned short(*)[72])QP;
    #pragma unroll
    for (int ni = 0; ni < 4; ni++)
      #pragma unroll
      for (int rg = 0; rg < 4; rg++) {
        float p = __expf(sacc[ni][rg] * 0.125f);
        lsum[rg] += p;
        Ps[wave * 16 + quad * 4 + rg][ni * 16 + l15] = f2bf(p);
      }

    Frag ap[2];
    #pragma unroll
    for (int kc = 0; kc < 2; kc++)
      ap[kc].v = *(const bf16x8*)&Ps[wave * 16 + l15][kc * 32 + quad * 8];

    #pragma unroll
    for (int nj = 0; nj < 4; nj++)
      #pragma unroll
      for (int kc = 0; kc < 2; kc++) {
        Frag bv;
        bv.v = *(const bf16x8*)&Vt[cur][kc][(nj * 16 + l15) * 32 + quad * 8];
        O[nj] = __builtin_amdgcn_mfma_f32_16x16x32_bf16(ap[kc].v, bv.v, O[nj], 0, 0, 0);
      }
  }

  float linv[4];
  #pragma unroll
  for (int rg = 0; rg < 4; rg++) {
    float l = lsum[rg];
    #pragma unroll
    for (int m = 1; m < 16; m <<= 1) l += __shfl_xor(l, m, 16);
    linv[rg] = 1.0f / l;
  }
  #pragma unroll
  for (int nj = 0; nj < 4; nj++)
    #pragma unroll
    for (int rg = 0; rg < 4; rg++) {
      int row = qt * 64 + wave * 16 + quad * 4 + rg;
      int col = nj * 16 + l15;
      ctx[baseQK + (size_t)row * Dm + col] = f2bf(O[nj][rg] * linv[rg]);
    }
}

extern "C" void kernel_launch(void* const* d_in, const int* in_sizes, int n_in,
                              void* d_out, int out_size, void* d_ws, size_t ws_size,
                              hipStream_t stream)
{
  const float* x      = (const float*)d_in[0];
  const float* Wq     = (const float*)d_in[1];
  const float* Wk     = (const float*)d_in[2];
  const float* Wv     = (const float*)d_in[3];
  const float* Wo     = (const float*)d_in[4];
  const float* bo     = (const float*)d_in[5];
  const float* scale1 = (const float*)d_in[6];
  const float* shift1 = (const float*)d_in[7];
  const float* scale2 = (const float*)d_in[8];
  const float* shift2 = (const float*)d_in[9];
  const float* centers= (const float*)d_in[10];
  const float* lsp    = (const float*)d_in[11];
  const float* Wf     = (const float*)d_in[12];
  const float* bfv    = (const float*)d_in[13];
  float* out = (float*)d_out;

  unsigned short* wsu = (unsigned short*)d_ws;
  unsigned short* wqT = wsu;
  unsigned short* wkT = wsu + WSZ;
  unsigned short* wvT = wsu + 2 * WSZ;
  unsigned short* woT = wsu + 3 * WSZ;
  unsigned short* wfT = wsu + 4 * WSZ;
  unsigned short* cb  = wsu + 5 * WSZ;
  unsigned short* bufA = wsu + 6 * WSZ;
  unsigned short* bufB = bufA + S;
  unsigned short* hb  = bufA;
  unsigned short* qb  = bufB;
  unsigned short* kb  = bufB + S;
  unsigned short* vbt = bufB + 2 * S;
  unsigned short* ctx = bufA;
  float* x1f          = (float*)bufB;
  unsigned short* hf  = bufB + 2 * S;
  unsigned short* Km  = bufA;
  float* hn = (float*)(bufB + 3 * S);
  float* cn = hn + ROWS;
  float* flags = cn + Dm;   // [0]=min(hn), [1]=max(cn)

  dim3 gg(Dm / 64, ROWS / 64);         // (12, 64)

  prep_kernel<<<2512, 256, 0, stream>>>(Wq, Wk, Wv, Wo, Wf, wsu,
                                        centers, lsp, cb, cn,
                                        x, scale1, shift1, hb);
  gemm_qkv<<<dim3(12, 64), 256, 0, stream>>>(hb, wqT, wkT, wvT, qb, kb, vbt);
  attn_flash<<<dim3(Ls / 64, Hh, Bb), 256, 0, stream>>>(qb, kb, vbt, ctx);
  gemm64<1><<<gg, 256, 0, stream>>>(ctx, woT, nullptr, x1f, x, bo, nullptr, nullptr, nullptr);
  ln2_kernel<<<ROWS / 4, 256, 0, stream>>>(x1f, scale2, shift2, lsp, hf, hn);
  reduce_flags<<<1, 256, 0, stream>>>(hn, cn, flags);
  gemm64<2><<<gg, 256, 0, stream>>>(hf, cb, Km, nullptr, nullptr, nullptr, hn, cn, flags);
  gemm64<3><<<gg, 256, 0, stream>>>(Km, wfT, nullptr, out, x1f, bfv, hn, cn, flags);
}

// Round 12
// 177.617 us; speedup vs baseline: 1.1067x; 1.0297x over previous
//
#include <hip/hip_runtime.h>

#define EPS_LN 1e-5f

constexpr int Dm   = 768;
constexpr int Bb   = 4;
constexpr int Ls   = 1024;
constexpr int Hh   = 12;
constexpr int HD   = 64;
constexpr int ROWS = Bb * Ls;            // 4096
constexpr size_t S = (size_t)ROWS * Dm;  // 3,145,728
constexpr size_t WSZ = (size_t)Dm * Dm;  // 589,824

typedef __attribute__((ext_vector_type(8))) short bf16x8;
typedef __attribute__((ext_vector_type(4))) float f32x4;
typedef const __attribute__((address_space(1))) unsigned int* gas_p;
typedef __attribute__((address_space(3))) unsigned int* las_p;

__device__ __forceinline__ unsigned short f2bf(float f) {
  unsigned int u = __float_as_uint(f);
  u += 0x7fffu + ((u >> 16) & 1u);   // RNE
  return (unsigned short)(u >> 16);
}
__device__ __forceinline__ void gl_lds16(const unsigned short* g, unsigned short* l) {
  __builtin_amdgcn_global_load_lds((gas_p)g, (las_p)l, 16, 0, 0);
}

// =============== fused prep: 5 weight transposes + centers + LN1 (wave-per-row) ===============
__global__ void __launch_bounds__(256) prep_kernel(
    const float* __restrict__ W0, const float* __restrict__ W1,
    const float* __restrict__ W2, const float* __restrict__ W3,
    const float* __restrict__ W4, unsigned short* __restrict__ wtBase,
    const float* __restrict__ centers, const float* __restrict__ ls,
    unsigned short* __restrict__ cb, float* __restrict__ cn,
    const float* __restrict__ x, const float* __restrict__ scale,
    const float* __restrict__ shift, unsigned short* __restrict__ hb)
{
  __shared__ float smem[64 * 65];
  int bx = blockIdx.x, t = threadIdx.x;
  if (bx < 720) {
    int w = bx / 144, rem = bx - w * 144;
    int ky = rem / 12, nx = rem - ky * 12;
    const float* W = w == 0 ? W0 : w == 1 ? W1 : w == 2 ? W2 : w == 3 ? W3 : W4;
    unsigned short* WT = wtBase + (size_t)w * WSZ;
    int k0 = ky * 64, n0 = nx * 64;
    int c = t & 63, r4 = t >> 6;
    #pragma unroll
    for (int p = 0; p < 16; p++) {
      int r = p * 4 + r4;
      smem[r * 65 + c] = W[(size_t)(k0 + r) * Dm + n0 + c];
    }
    __syncthreads();
    #pragma unroll
    for (int p = 0; p < 16; p++) {
      int r = p * 4 + r4;
      WT[(size_t)(n0 + r) * Dm + k0 + c] = f2bf(smem[c * 65 + r]);
    }
  } else if (bx < 1488) {
    int j = bx - 720;
    float s = 0.f;
    #pragma unroll
    for (int i = 0; i < 3; i++) {
      int k = t + 256 * i;
      float c = centers[(size_t)j * Dm + k] / ls[k];
      cb[(size_t)j * Dm + k] = f2bf(c);
      s += c * c;
    }
    smem[t] = s; __syncthreads();
    for (int o = 128; o > 0; o >>= 1) { if (t < o) smem[t] += smem[t + o]; __syncthreads(); }
    if (t == 0) cn[j] = smem[0];
  } else {
    // LN1: wave-per-row, zero barriers
    int lane = t & 63;
    int row = (bx - 1488) * 4 + (t >> 6);
    size_t base = (size_t)row * Dm;
    float4 v[3];
    #pragma unroll
    for (int j = 0; j < 3; j++)
      v[j] = *(const float4*)&x[base + 4 * (lane + 64 * j)];
    float sum = 0.f;
    #pragma unroll
    for (int j = 0; j < 3; j++) sum += v[j].x + v[j].y + v[j].z + v[j].w;
    #pragma unroll
    for (int m = 1; m < 64; m <<= 1) sum += __shfl_xor(sum, m);
    float mean = sum * (1.0f / Dm);
    float4 d[3];
    float vs = 0.f;
    #pragma unroll
    for (int j = 0; j < 3; j++) {
      d[j].x = v[j].x - mean; d[j].y = v[j].y - mean;
      d[j].z = v[j].z - mean; d[j].w = v[j].w - mean;
      vs += d[j].x*d[j].x + d[j].y*d[j].y + d[j].z*d[j].z + d[j].w*d[j].w;
    }
    #pragma unroll
    for (int m = 1; m < 64; m <<= 1) vs += __shfl_xor(vs, m);
    float rstd = rsqrtf(vs * (1.0f / Dm) + EPS_LN);
    #pragma unroll
    for (int j = 0; j < 3; j++) {
      int c4 = 4 * (lane + 64 * j);
      float4 sc = *(const float4*)&scale[c4];
      float4 sh = *(const float4*)&shift[c4];
      ushort4 o4;
      o4.x = f2bf(sc.x * d[j].x * rstd + sh.x);
      o4.y = f2bf(sc.y * d[j].y * rstd + sh.y);
      o4.z = f2bf(sc.z * d[j].z * rstd + sh.z);
      o4.w = f2bf(sc.w * d[j].w * rstd + sh.w);
      *(ushort4*)&hb[base + c4] = o4;
    }
  }
}

// ---- LN2 + /ls (wave-per-row, zero barriers) + fused degenerate-RBF output ----
// Each wave redundantly computes cmax = max(cn[0..767]) (L2-hot, 12 loads + 6 shfls).
// If this ROW is degenerate (sqrt(hn_row) - sqrt(cmax))^2 > 300, then its Km row is
// EXACTLY zero (fp32 exp(-x)==0 for x>=104; sq >= 208 guaranteed, Cauchy-Schwarz) so
// out = x1 + bias — written here from registers, letting gemm64<3> skip its pass.
// If globally non-degenerate, gemm64<3> overwrites all rows with identical values.
__global__ void __launch_bounds__(256) ln2_kernel(
    const float* __restrict__ xin, const float* __restrict__ scale,
    const float* __restrict__ shift, const float* __restrict__ ls,
    const float* __restrict__ cn, const float* __restrict__ bias,
    unsigned short* __restrict__ o, float* __restrict__ hn,
    float* __restrict__ outF)
{
  int lane = threadIdx.x & 63;
  int row = blockIdx.x * 4 + (threadIdx.x >> 6);
  size_t base = (size_t)row * Dm;
  float4 v[3];
  #pragma unroll
  for (int j = 0; j < 3; j++)
    v[j] = *(const float4*)&xin[base + 4 * (lane + 64 * j)];
  float sum = 0.f;
  #pragma unroll
  for (int j = 0; j < 3; j++) sum += v[j].x + v[j].y + v[j].z + v[j].w;
  #pragma unroll
  for (int m = 1; m < 64; m <<= 1) sum += __shfl_xor(sum, m);
  float mean = sum * (1.0f / Dm);
  float4 d[3];
  float vs = 0.f;
  #pragma unroll
  for (int j = 0; j < 3; j++) {
    d[j].x = v[j].x - mean; d[j].y = v[j].y - mean;
    d[j].z = v[j].z - mean; d[j].w = v[j].w - mean;
    vs += d[j].x*d[j].x + d[j].y*d[j].y + d[j].z*d[j].z + d[j].w*d[j].w;
  }
  #pragma unroll
  for (int m = 1; m < 64; m <<= 1) vs += __shfl_xor(vs, m);
  float rstd = rsqrtf(vs * (1.0f / Dm) + EPS_LN);
  float hsum = 0.f;
  #pragma unroll
  for (int j = 0; j < 3; j++) {
    int c4 = 4 * (lane + 64 * j);
    float4 sc = *(const float4*)&scale[c4];
    float4 sh = *(const float4*)&shift[c4];
    float4 lv = *(const float4*)&ls[c4];
    float4 hv;
    hv.x = (sc.x * d[j].x * rstd + sh.x) / lv.x;
    hv.y = (sc.y * d[j].y * rstd + sh.y) / lv.y;
    hv.z = (sc.z * d[j].z * rstd + sh.z) / lv.z;
    hv.w = (sc.w * d[j].w * rstd + sh.w) / lv.w;
    ushort4 o4;
    o4.x = f2bf(hv.x); o4.y = f2bf(hv.y); o4.z = f2bf(hv.z); o4.w = f2bf(hv.w);
    *(ushort4*)&o[base + c4] = o4;
    hsum += hv.x*hv.x + hv.y*hv.y + hv.z*hv.z + hv.w*hv.w;
  }
  #pragma unroll
  for (int m = 1; m < 64; m <<= 1) hsum += __shfl_xor(hsum, m);
  if (lane == 0) hn[row] = hsum;

  // per-wave cmax over cn[768] (order-independent fmax; all lanes end with same hsum)
  float cm = 0.f;
  #pragma unroll
  for (int j = 0; j < 12; j++) cm = fmaxf(cm, cn[lane + 64 * j]);
  #pragma unroll
  for (int m = 1; m < 64; m <<= 1) cm = fmaxf(cm, __shfl_xor(cm, m));
  float a = sqrtf(hsum), bq = sqrtf(cm);
  if ((a > bq) && ((a - bq) * (a - bq) > 300.0f)) {
    #pragma unroll
    for (int j = 0; j < 3; j++) {
      int c4 = 4 * (lane + 64 * j);
      float4 xv = v[j];  // careful: need original x1f, recompute from v (v holds xin row)
      float4 bv = *(const float4*)&bias[c4];
      float4 ov;
      ov.x = xv.x + bv.x; ov.y = xv.y + bv.y; ov.z = xv.z + bv.z; ov.w = xv.w + bv.w;
      *(float4*)&outF[base + c4] = ov;
    }
  }
}

// ---- 1-block reduce: flags[0]=min(hn), flags[1]=max(cn) (order-independent) ----
__global__ void __launch_bounds__(256) reduce_flags(
    const float* __restrict__ hn, const float* __restrict__ cn,
    float* __restrict__ flags)
{
  __shared__ float r2[256];
  int t = threadIdx.x;
  float mn = 1e30f;
  for (int i = t; i < ROWS; i += 256) mn = fminf(mn, hn[i]);
  r2[t] = mn; __syncthreads();
  for (int o = 128; o > 0; o >>= 1) { if (t < o) r2[t] = fminf(r2[t], r2[t + o]); __syncthreads(); }
  if (t == 0) flags[0] = r2[0];
  __syncthreads();
  float mx = 0.f;
  for (int i = t; i < Dm; i += 256) mx = fmaxf(mx, cn[i]);
  r2[t] = mx; __syncthreads();
  for (int o = 128; o > 0; o >>= 1) { if (t < o) r2[t] = fmaxf(r2[t], r2[t + o]); __syncthreads(); }
  if (t == 0) flags[1] = r2[0];
}

// =============== QKV 3-in-1 GEMM (R0-proven; 128^2 variant refuted twice) ===============
__global__ void __launch_bounds__(256) gemm_qkv(
    const unsigned short* __restrict__ Abf,
    const unsigned short* __restrict__ wqT,
    const unsigned short* __restrict__ wkT,
    const unsigned short* __restrict__ wvT,
    unsigned short* __restrict__ qb,
    unsigned short* __restrict__ kb,
    unsigned short* __restrict__ vbt)
{
  int m0 = blockIdx.y * 64, n0 = blockIdx.x * 64;
  __shared__ unsigned short sm[4096 + 3 * 4096];
  int tid = threadIdx.x;
  int lane = tid & 63, wave = tid >> 6;
  int quad = lane >> 4, l15 = lane & 15;
  int wr = (wave >> 1) << 5, wc = (wave & 1) << 5;

  f32x4 acc[3][2][2];
  #pragma unroll
  for (int w = 0; w < 3; w++)
    #pragma unroll
    for (int i = 0; i < 2; i++)
      #pragma unroll
      for (int j = 0; j < 2; j++) acc[w][i][j] = (f32x4){0.f, 0.f, 0.f, 0.f};

  const unsigned short* gA = Abf + (size_t)(m0 + (tid >> 2)) * Dm + ((tid & 3) << 3);
  size_t bOff = (size_t)(n0 + (tid >> 2)) * Dm + ((tid & 3) << 3);
  const unsigned short* gB[3] = { wqT + bOff, wkT + bOff, wvT + bOff };

  union Frag { bf16x8 v; ushort4 h[2]; };

  for (int k0 = 0; k0 < Dm; k0 += 64) {
    gl_lds16(gA + k0,      &sm[tid * 8]);
    gl_lds16(gA + k0 + 32, &sm[2048 + tid * 8]);
    #pragma unroll
    for (int w = 0; w < 3; w++) {
      gl_lds16(gB[w] + k0,      &sm[4096 + w * 4096 + tid * 8]);
      gl_lds16(gB[w] + k0 + 32, &sm[4096 + w * 4096 + 2048 + tid * 8]);
    }
    __syncthreads();
    Frag af[2][2];
    #pragma unroll
    for (int kc = 0; kc < 2; kc++)
      #pragma unroll
      for (int mi = 0; mi < 2; mi++)
        af[kc][mi].v = *(const bf16x8*)&sm[kc * 2048 + (wr + mi * 16 + l15) * 32 + quad * 8];
    #pragma unroll
    for (int w = 0; w < 3; w++)
      #pragma unroll
      for (int kc = 0; kc < 2; kc++)
        #pragma unroll
        for (int ni = 0; ni < 2; ni++) {
          Frag bf;
          bf.v = *(const bf16x8*)&sm[4096 + w * 4096 + kc * 2048 + (wc + ni * 16 + l15) * 32 + quad * 8];
          #pragma unroll
          for (int mi = 0; mi < 2; mi++)
            acc[w][mi][ni] = __builtin_amdgcn_mfma_f32_16x16x32_bf16(
                af[kc][mi].v, bf.v, acc[w][mi][ni], 0, 0, 0);
        }
    __syncthreads();
  }

  #pragma unroll
  for (int w = 0; w < 2; w++) {
    unsigned short* ob = w ? kb : qb;
    #pragma unroll
    for (int mi = 0; mi < 2; mi++)
      #pragma unroll
      for (int ni = 0; ni < 2; ni++)
        #pragma unroll
        for (int rg = 0; rg < 4; rg++) {
          int gr = m0 + wr + mi * 16 + quad * 4 + rg;
          int gc = n0 + wc + ni * 16 + l15;
          ob[(size_t)gr * Dm + gc] = f2bf(acc[w][mi][ni][rg]);
        }
  }
  #pragma unroll
  for (int mi = 0; mi < 2; mi++)
    #pragma unroll
    for (int ni = 0; ni < 2; ni++)
      #pragma unroll
      for (int rg = 0; rg < 4; rg++) {
        int rl = wr + mi * 16 + quad * 4 + rg;
        int cl = wc + ni * 16 + l15;
        sm[cl * 72 + rl] = f2bf(acc[2][mi][ni][rg]);
      }
  __syncthreads();
  {
    int d = tid >> 2, c0 = (tid & 3) * 16;
    int b_ = m0 >> 10, keybase = m0 & 1023;
    unsigned short* dst = vbt + ((size_t)((blockIdx.x * 4 + b_) * 64 + d)) * 1024 + keybase + c0;
    #pragma unroll
    for (int i = 0; i < 16; i += 4)
      *(ushort4*)(dst + i) = *(const ushort4*)&sm[d * 72 + c0 + i];
  }
}

// =============== MFMA bf16 GEMM, 64x64 tile, BK=64 (modes 1..3) ===============
// MODE>=2 degeneracy: flags[0]=min(hn), flags[1]=max(cn) from reduce_flags.
// Degenerate: MODE 2 -> Km==0, nobody reads it; MODE 3 -> out already written by
// ln2's fused per-row path (global allz implies every row's per-row test passed).
template<int MODE>
__global__ void __launch_bounds__(256) gemm64(
    const unsigned short* __restrict__ Abf,
    const unsigned short* __restrict__ BT,
    unsigned short* __restrict__ o0,
    float* __restrict__ outF,
    const float* __restrict__ residF,
    const float* __restrict__ biasF,
    const float* __restrict__ hn,
    const float* __restrict__ cn,
    const float* __restrict__ flags)
{
  __shared__ unsigned short Asm[2][2048];
  __shared__ unsigned short Bsm[2][2048];
  int tid = threadIdx.x;
  int m0 = blockIdx.y * 64, n0 = blockIdx.x * 64;

  if (MODE >= 2) {
    float hmin = flags[0];
    float cmax = flags[1];
    float a = sqrtf(hmin), bq = sqrtf(cmax);
    bool allz = (a > bq) && ((a - bq) * (a - bq) > 300.0f);
    if (allz) return;
  }

  int lane = tid & 63, wave = tid >> 6;
  int quad = lane >> 4, l15 = lane & 15;
  int wr = (wave >> 1) << 5, wc = (wave & 1) << 5;

  f32x4 acc[2][2];
  #pragma unroll
  for (int i = 0; i < 2; i++)
    #pragma unroll
    for (int j = 0; j < 2; j++) acc[i][j] = (f32x4){0.f, 0.f, 0.f, 0.f};

  const unsigned short* gA = Abf + (size_t)(m0 + (tid >> 2)) * Dm + ((tid & 3) << 3);
  const unsigned short* gB = BT  + (size_t)(n0 + (tid >> 2)) * Dm + ((tid & 3) << 3);

  union Frag { bf16x8 v; ushort4 h[2]; };

  for (int k0 = 0; k0 < Dm; k0 += 64) {
    gl_lds16(gA + k0,      &Asm[0][tid * 8]);
    gl_lds16(gA + k0 + 32, &Asm[1][tid * 8]);
    gl_lds16(gB + k0,      &Bsm[0][tid * 8]);
    gl_lds16(gB + k0 + 32, &Bsm[1][tid * 8]);
    __syncthreads();
    #pragma unroll
    for (int kc = 0; kc < 2; kc++) {
      Frag af[2], bfb[2];
      #pragma unroll
      for (int i = 0; i < 2; i++) {
        af[i].v  = *(const bf16x8*)&Asm[kc][(wr + i * 16 + l15) * 32 + quad * 8];
        bfb[i].v = *(const bf16x8*)&Bsm[kc][(wc + i * 16 + l15) * 32 + quad * 8];
      }
      #pragma unroll
      for (int mi = 0; mi < 2; mi++)
        #pragma unroll
        for (int ni = 0; ni < 2; ni++)
          acc[mi][ni] = __builtin_amdgcn_mfma_f32_16x16x32_bf16(
              af[mi].v, bfb[ni].v, acc[mi][ni], 0, 0, 0);
    }
    __syncthreads();
  }

  #pragma unroll
  for (int mi = 0; mi < 2; mi++)
    #pragma unroll
    for (int ni = 0; ni < 2; ni++)
      #pragma unroll
      for (int rg = 0; rg < 4; rg++) {
        int gr = m0 + wr + mi * 16 + quad * 4 + rg;
        int gc = n0 + wc + ni * 16 + l15;
        size_t idx = (size_t)gr * Dm + gc;
        float v = acc[mi][ni][rg];
        if (MODE == 2) {
          float sq = fmaxf(hn[gr] + cn[gc] - 2.0f * v, 0.f);
          o0[idx] = f2bf(__expf(-0.5f * sq));
        } else {
          outF[idx] = residF[idx] + v + biasF[gc];
        }
      }
}

// =============== flash attention v6 (R9): 2-phase prefetch, double-buffered K/V ===============
__global__ void __launch_bounds__(256) attn_flash(
    const unsigned short* __restrict__ q,
    const unsigned short* __restrict__ k,
    const unsigned short* __restrict__ vbt,
    unsigned short* __restrict__ ctx)
{
  int bx = blockIdx.x;
  int qt = (bx & 1) ? (15 - (bx >> 1)) : (bx >> 1);
  int h  = blockIdx.y;
  int b  = blockIdx.z;
  int tid = threadIdx.x;
  int lane = tid & 63, wave = tid >> 6;
  int quad = lane >> 4, l15 = lane & 15;

  __shared__ unsigned short Ks[2][2][2048];   // [buf][kc]
  __shared__ unsigned short Vt[2][2][2048];
  __shared__ unsigned short QP[4608];

  size_t baseQK = (size_t)(b * Ls) * Dm + h * HD;
  const unsigned short* gVt = vbt + (size_t)((h * 4 + b) * 64 + (tid >> 2)) * 1024 + ((tid & 3) << 3);

  {
    const unsigned short* gQ = q + baseQK + (size_t)(qt * 64 + (tid >> 2)) * Dm + ((tid & 3) << 3);
    gl_lds16(gQ,      &QP[tid * 8]);
    gl_lds16(gQ + 32, &QP[2048 + tid * 8]);
  }
  __syncthreads();

  union Frag { bf16x8 v; ushort4 h[2]; };
  Frag afq[2];
  #pragma unroll
  for (int kc = 0; kc < 2; kc++)
    afq[kc].v = *(const bf16x8*)&QP[kc * 2048 + (wave * 16 + l15) * 32 + quad * 8];
  asm volatile("s_waitcnt lgkmcnt(0)" ::: "memory");

  f32x4 O[4];
  #pragma unroll
  for (int nj = 0; nj < 4; nj++) O[nj] = (f32x4){0.f, 0.f, 0.f, 0.f};
  float lsum[4] = {0.f, 0.f, 0.f, 0.f};

  const unsigned short* gK = k + baseQK + (size_t)(tid >> 2) * Dm + ((tid & 3) << 3);

  gl_lds16(gK,      &Ks[0][0][tid * 8]);
  gl_lds16(gK + 32, &Ks[0][1][tid * 8]);
  gl_lds16(gVt,      &Vt[0][0][tid * 8]);
  gl_lds16(gVt + 32, &Vt[0][1][tid * 8]);

  for (int kt = 0; kt <= qt; kt++) {
    int cur = kt & 1;
    asm volatile("s_waitcnt lgkmcnt(0)" ::: "memory");
    __builtin_amdgcn_s_barrier();
    if (kt < qt) {
      int nxt = cur ^ 1;
      gl_lds16(gK + (size_t)((kt + 1) * 64) * Dm,      &Ks[nxt][0][tid * 8]);
      gl_lds16(gK + (size_t)((kt + 1) * 64) * Dm + 32, &Ks[nxt][1][tid * 8]);
      gl_lds16(gVt + (kt + 1) * 64,      &Vt[nxt][0][tid * 8]);
      gl_lds16(gVt + (kt + 1) * 64 + 32, &Vt[nxt][1][tid * 8]);
      asm volatile("s_waitcnt vmcnt(4)" ::: "memory");
    } else {
      asm volatile("s_waitcnt vmcnt(0)" ::: "memory");
    }
    __builtin_amdgcn_s_barrier();
    __builtin_amdgcn_sched_barrier(0);

    f32x4 sacc[4];
    #pragma unroll
    for (int ni = 0; ni < 4; ni++) {
      sacc[ni] = (f32x4){0.f, 0.f, 0.f, 0.f};
      #pragma unroll
      for (int kc = 0; kc < 2; kc++) {
        Frag bk;
        bk.v = *(const bf16x8*)&Ks[cur][kc][(ni * 16 + l15) * 32 + quad * 8];
        sacc[ni] = __builtin_amdgcn_mfma_f32_16x16x32_bf16(afq[kc].v, bk.v, sacc[ni], 0, 0, 0);
      }
    }

    if (kt == qt) {
      #pragma unroll
      for (int ni = 0; ni < 4; ni++)
        #pragma unroll
        for (int rg = 0; rg < 4; rg++) {
          int rowl = wave * 16 + quad * 4 + rg;
          int coll = ni * 16 + l15;
          if (coll > rowl) sacc[ni][rg] = -1e30f;
        }
    }

    unsigned short (*Ps)[72] = (unsigned short(*)[72])QP;
    #pragma unroll
    for (int ni = 0; ni < 4; ni++)
      #pragma unroll
      for (int rg = 0; rg < 4; rg++) {
        float p = __expf(sacc[ni][rg] * 0.125f);
        lsum[rg] += p;
        Ps[wave * 16 + quad * 4 + rg][ni * 16 + l15] = f2bf(p);
      }

    Frag ap[2];
    #pragma unroll
    for (int kc = 0; kc < 2; kc++)
      ap[kc].v = *(const bf16x8*)&Ps[wave * 16 + l15][kc * 32 + quad * 8];

    #pragma unroll
    for (int nj = 0; nj < 4; nj++)
      #pragma unroll
      for (int kc = 0; kc < 2; kc++) {
        Frag bv;
        bv.v = *(const bf16x8*)&Vt[cur][kc][(nj * 16 + l15) * 32 + quad * 8];
        O[nj] = __builtin_amdgcn_mfma_f32_16x16x32_bf16(ap[kc].v, bv.v, O[nj], 0, 0, 0);
      }
  }

  float linv[4];
  #pragma unroll
  for (int rg = 0; rg < 4; rg++) {
    float l = lsum[rg];
    #pragma unroll
    for (int m = 1; m < 16; m <<= 1) l += __shfl_xor(l, m, 16);
    linv[rg] = 1.0f / l;
  }
  #pragma unroll
  for (int nj = 0; nj < 4; nj++)
    #pragma unroll
    for (int rg = 0; rg < 4; rg++) {
      int row = qt * 64 + wave * 16 + quad * 4 + rg;
      int col = nj * 16 + l15;
      ctx[baseQK + (size_t)row * Dm + col] = f2bf(O[nj][rg] * linv[rg]);
    }
}

extern "C" void kernel_launch(void* const* d_in, const int* in_sizes, int n_in,
                              void* d_out, int out_size, void* d_ws, size_t ws_size,
                              hipStream_t stream)
{
  const float* x      = (const float*)d_in[0];
  const float* Wq     = (const float*)d_in[1];
  const float* Wk     = (const float*)d_in[2];
  const float* Wv     = (const float*)d_in[3];
  const float* Wo     = (const float*)d_in[4];
  const float* bo     = (const float*)d_in[5];
  const float* scale1 = (const float*)d_in[6];
  const float* shift1 = (const float*)d_in[7];
  const float* scale2 = (const float*)d_in[8];
  const float* shift2 = (const float*)d_in[9];
  const float* centers= (const float*)d_in[10];
  const float* lsp    = (const float*)d_in[11];
  const float* Wf     = (const float*)d_in[12];
  const float* bfv    = (const float*)d_in[13];
  float* out = (float*)d_out;

  unsigned short* wsu = (unsigned short*)d_ws;
  unsigned short* wqT = wsu;
  unsigned short* wkT = wsu + WSZ;
  unsigned short* wvT = wsu + 2 * WSZ;
  unsigned short* woT = wsu + 3 * WSZ;
  unsigned short* wfT = wsu + 4 * WSZ;
  unsigned short* cb  = wsu + 5 * WSZ;
  unsigned short* bufA = wsu + 6 * WSZ;
  unsigned short* bufB = bufA + S;
  unsigned short* hb  = bufA;
  unsigned short* qb  = bufB;
  unsigned short* kb  = bufB + S;
  unsigned short* vbt = bufB + 2 * S;
  unsigned short* ctx = bufA;
  float* x1f          = (float*)bufB;
  unsigned short* hf  = bufB + 2 * S;
  unsigned short* Km  = bufA;
  float* hn = (float*)(bufB + 3 * S);
  float* cn = hn + ROWS;
  float* flags = cn + Dm;   // [0]=min(hn), [1]=max(cn)

  dim3 gg(Dm / 64, ROWS / 64);         // (12, 64)

  prep_kernel<<<2512, 256, 0, stream>>>(Wq, Wk, Wv, Wo, Wf, wsu,
                                        centers, lsp, cb, cn,
                                        x, scale1, shift1, hb);
  gemm_qkv<<<dim3(12, 64), 256, 0, stream>>>(hb, wqT, wkT, wvT, qb, kb, vbt);
  attn_flash<<<dim3(Ls / 64, Hh, Bb), 256, 0, stream>>>(qb, kb, vbt, ctx);
  gemm64<1><<<gg, 256, 0, stream>>>(ctx, woT, nullptr, x1f, x, bo, nullptr, nullptr, nullptr);
  ln2_kernel<<<ROWS / 4, 256, 0, stream>>>(x1f, scale2, shift2, lsp, cn, bfv, hf, hn, out);
  reduce_flags<<<1, 256, 0, stream>>>(hn, cn, flags);
  gemm64<2><<<gg, 256, 0, stream>>>(hf, cb, Km, nullptr, nullptr, nullptr, hn, cn, flags);
  gemm64<3><<<gg, 256, 0, stream>>>(Km, wfT, nullptr, out, x1f, bfv, hn, cn, flags);
}

// Round 13
// 176.461 us; speedup vs baseline: 1.1140x; 1.0066x over previous
//
#include <hip/hip_runtime.h>

#define EPS_LN 1e-5f

constexpr int Dm   = 768;
constexpr int Bb   = 4;
constexpr int Ls   = 1024;
constexpr int Hh   = 12;
constexpr int HD   = 64;
constexpr int ROWS = Bb * Ls;            // 4096
constexpr size_t S = (size_t)ROWS * Dm;  // 3,145,728
constexpr size_t WSZ = (size_t)Dm * Dm;  // 589,824

typedef __attribute__((ext_vector_type(8))) short bf16x8;
typedef __attribute__((ext_vector_type(4))) float f32x4;
typedef const __attribute__((address_space(1))) unsigned int* gas_p;
typedef __attribute__((address_space(3))) unsigned int* las_p;

__device__ __forceinline__ unsigned short f2bf(float f) {
  unsigned int u = __float_as_uint(f);
  u += 0x7fffu + ((u >> 16) & 1u);   // RNE
  return (unsigned short)(u >> 16);
}
__device__ __forceinline__ void gl_lds16(const unsigned short* g, unsigned short* l) {
  __builtin_amdgcn_global_load_lds((gas_p)g, (las_p)l, 16, 0, 0);
}

// =============== fused prep: 5 weight transposes + centers + LN1 (wave-per-row) ===============
__global__ void __launch_bounds__(256) prep_kernel(
    const float* __restrict__ W0, const float* __restrict__ W1,
    const float* __restrict__ W2, const float* __restrict__ W3,
    const float* __restrict__ W4, unsigned short* __restrict__ wtBase,
    const float* __restrict__ centers, const float* __restrict__ ls,
    unsigned short* __restrict__ cb, float* __restrict__ cn,
    const float* __restrict__ x, const float* __restrict__ scale,
    const float* __restrict__ shift, unsigned short* __restrict__ hb)
{
  __shared__ float smem[64 * 65];
  int bx = blockIdx.x, t = threadIdx.x;
  if (bx < 720) {
    int w = bx / 144, rem = bx - w * 144;
    int ky = rem / 12, nx = rem - ky * 12;
    const float* W = w == 0 ? W0 : w == 1 ? W1 : w == 2 ? W2 : w == 3 ? W3 : W4;
    unsigned short* WT = wtBase + (size_t)w * WSZ;
    int k0 = ky * 64, n0 = nx * 64;
    int c = t & 63, r4 = t >> 6;
    #pragma unroll
    for (int p = 0; p < 16; p++) {
      int r = p * 4 + r4;
      smem[r * 65 + c] = W[(size_t)(k0 + r) * Dm + n0 + c];
    }
    __syncthreads();
    #pragma unroll
    for (int p = 0; p < 16; p++) {
      int r = p * 4 + r4;
      WT[(size_t)(n0 + r) * Dm + k0 + c] = f2bf(smem[c * 65 + r]);
    }
  } else if (bx < 1488) {
    int j = bx - 720;
    float s = 0.f;
    #pragma unroll
    for (int i = 0; i < 3; i++) {
      int k = t + 256 * i;
      float c = centers[(size_t)j * Dm + k] / ls[k];
      cb[(size_t)j * Dm + k] = f2bf(c);
      s += c * c;
    }
    smem[t] = s; __syncthreads();
    for (int o = 128; o > 0; o >>= 1) { if (t < o) smem[t] += smem[t + o]; __syncthreads(); }
    if (t == 0) cn[j] = smem[0];
  } else {
    // LN1: wave-per-row, zero barriers
    int lane = t & 63;
    int row = (bx - 1488) * 4 + (t >> 6);
    size_t base = (size_t)row * Dm;
    float4 v[3];
    #pragma unroll
    for (int j = 0; j < 3; j++)
      v[j] = *(const float4*)&x[base + 4 * (lane + 64 * j)];
    float sum = 0.f;
    #pragma unroll
    for (int j = 0; j < 3; j++) sum += v[j].x + v[j].y + v[j].z + v[j].w;
    #pragma unroll
    for (int m = 1; m < 64; m <<= 1) sum += __shfl_xor(sum, m);
    float mean = sum * (1.0f / Dm);
    float4 d[3];
    float vs = 0.f;
    #pragma unroll
    for (int j = 0; j < 3; j++) {
      d[j].x = v[j].x - mean; d[j].y = v[j].y - mean;
      d[j].z = v[j].z - mean; d[j].w = v[j].w - mean;
      vs += d[j].x*d[j].x + d[j].y*d[j].y + d[j].z*d[j].z + d[j].w*d[j].w;
    }
    #pragma unroll
    for (int m = 1; m < 64; m <<= 1) vs += __shfl_xor(vs, m);
    float rstd = rsqrtf(vs * (1.0f / Dm) + EPS_LN);
    #pragma unroll
    for (int j = 0; j < 3; j++) {
      int c4 = 4 * (lane + 64 * j);
      float4 sc = *(const float4*)&scale[c4];
      float4 sh = *(const float4*)&shift[c4];
      ushort4 o4;
      o4.x = f2bf(sc.x * d[j].x * rstd + sh.x);
      o4.y = f2bf(sc.y * d[j].y * rstd + sh.y);
      o4.z = f2bf(sc.z * d[j].z * rstd + sh.z);
      o4.w = f2bf(sc.w * d[j].w * rstd + sh.w);
      *(ushort4*)&hb[base + c4] = o4;
    }
  }
}

// ---- LN2 + /ls (wave-per-row) + fused degenerate-RBF output (R12-proven) ----
__global__ void __launch_bounds__(256) ln2_kernel(
    const float* __restrict__ xin, const float* __restrict__ scale,
    const float* __restrict__ shift, const float* __restrict__ ls,
    const float* __restrict__ cn, const float* __restrict__ bias,
    unsigned short* __restrict__ o, float* __restrict__ hn,
    float* __restrict__ outF)
{
  int lane = threadIdx.x & 63;
  int row = blockIdx.x * 4 + (threadIdx.x >> 6);
  size_t base = (size_t)row * Dm;
  float4 v[3];
  #pragma unroll
  for (int j = 0; j < 3; j++)
    v[j] = *(const float4*)&xin[base + 4 * (lane + 64 * j)];
  float sum = 0.f;
  #pragma unroll
  for (int j = 0; j < 3; j++) sum += v[j].x + v[j].y + v[j].z + v[j].w;
  #pragma unroll
  for (int m = 1; m < 64; m <<= 1) sum += __shfl_xor(sum, m);
  float mean = sum * (1.0f / Dm);
  float4 d[3];
  float vs = 0.f;
  #pragma unroll
  for (int j = 0; j < 3; j++) {
    d[j].x = v[j].x - mean; d[j].y = v[j].y - mean;
    d[j].z = v[j].z - mean; d[j].w = v[j].w - mean;
    vs += d[j].x*d[j].x + d[j].y*d[j].y + d[j].z*d[j].z + d[j].w*d[j].w;
  }
  #pragma unroll
  for (int m = 1; m < 64; m <<= 1) vs += __shfl_xor(vs, m);
  float rstd = rsqrtf(vs * (1.0f / Dm) + EPS_LN);
  float hsum = 0.f;
  #pragma unroll
  for (int j = 0; j < 3; j++) {
    int c4 = 4 * (lane + 64 * j);
    float4 sc = *(const float4*)&scale[c4];
    float4 sh = *(const float4*)&shift[c4];
    float4 lv = *(const float4*)&ls[c4];
    float4 hv;
    hv.x = (sc.x * d[j].x * rstd + sh.x) / lv.x;
    hv.y = (sc.y * d[j].y * rstd + sh.y) / lv.y;
    hv.z = (sc.z * d[j].z * rstd + sh.z) / lv.z;
    hv.w = (sc.w * d[j].w * rstd + sh.w) / lv.w;
    ushort4 o4;
    o4.x = f2bf(hv.x); o4.y = f2bf(hv.y); o4.z = f2bf(hv.z); o4.w = f2bf(hv.w);
    *(ushort4*)&o[base + c4] = o4;
    hsum += hv.x*hv.x + hv.y*hv.y + hv.z*hv.z + hv.w*hv.w;
  }
  #pragma unroll
  for (int m = 1; m < 64; m <<= 1) hsum += __shfl_xor(hsum, m);
  if (lane == 0) hn[row] = hsum;

  float cm = 0.f;
  #pragma unroll
  for (int j = 0; j < 12; j++) cm = fmaxf(cm, cn[lane + 64 * j]);
  #pragma unroll
  for (int m = 1; m < 64; m <<= 1) cm = fmaxf(cm, __shfl_xor(cm, m));
  float a = sqrtf(hsum), bq = sqrtf(cm);
  if ((a > bq) && ((a - bq) * (a - bq) > 300.0f)) {
    #pragma unroll
    for (int j = 0; j < 3; j++) {
      int c4 = 4 * (lane + 64 * j);
      float4 xv = v[j];
      float4 bv = *(const float4*)&bias[c4];
      float4 ov;
      ov.x = xv.x + bv.x; ov.y = xv.y + bv.y; ov.z = xv.z + bv.z; ov.w = xv.w + bv.w;
      *(float4*)&outF[base + c4] = ov;
    }
  }
}

// ---- 1-block reduce: flags[0]=min(hn), flags[1]=max(cn) (order-independent) ----
__global__ void __launch_bounds__(256) reduce_flags(
    const float* __restrict__ hn, const float* __restrict__ cn,
    float* __restrict__ flags)
{
  __shared__ float r2[256];
  int t = threadIdx.x;
  float mn = 1e30f;
  for (int i = t; i < ROWS; i += 256) mn = fminf(mn, hn[i]);
  r2[t] = mn; __syncthreads();
  for (int o = 128; o > 0; o >>= 1) { if (t < o) r2[t] = fminf(r2[t], r2[t + o]); __syncthreads(); }
  if (t == 0) flags[0] = r2[0];
  __syncthreads();
  float mx = 0.f;
  for (int i = t; i < Dm; i += 256) mx = fmaxf(mx, cn[i]);
  r2[t] = mx; __syncthreads();
  for (int o = 128; o > 0; o >>= 1) { if (t < o) r2[t] = fmaxf(r2[t], r2[t + o]); __syncthreads(); }
  if (t == 0) flags[1] = r2[0];
}

// =============== QKV 3-in-1 GEMM (R0-proven) ===============
__global__ void __launch_bounds__(256) gemm_qkv(
    const unsigned short* __restrict__ Abf,
    const unsigned short* __restrict__ wqT,
    const unsigned short* __restrict__ wkT,
    const unsigned short* __restrict__ wvT,
    unsigned short* __restrict__ qb,
    unsigned short* __restrict__ kb,
    unsigned short* __restrict__ vbt)
{
  int m0 = blockIdx.y * 64, n0 = blockIdx.x * 64;
  __shared__ unsigned short sm[4096 + 3 * 4096];
  int tid = threadIdx.x;
  int lane = tid & 63, wave = tid >> 6;
  int quad = lane >> 4, l15 = lane & 15;
  int wr = (wave >> 1) << 5, wc = (wave & 1) << 5;

  f32x4 acc[3][2][2];
  #pragma unroll
  for (int w = 0; w < 3; w++)
    #pragma unroll
    for (int i = 0; i < 2; i++)
      #pragma unroll
      for (int j = 0; j < 2; j++) acc[w][i][j] = (f32x4){0.f, 0.f, 0.f, 0.f};

  const unsigned short* gA = Abf + (size_t)(m0 + (tid >> 2)) * Dm + ((tid & 3) << 3);
  size_t bOff = (size_t)(n0 + (tid >> 2)) * Dm + ((tid & 3) << 3);
  const unsigned short* gB[3] = { wqT + bOff, wkT + bOff, wvT + bOff };

  union Frag { bf16x8 v; ushort4 h[2]; };

  for (int k0 = 0; k0 < Dm; k0 += 64) {
    gl_lds16(gA + k0,      &sm[tid * 8]);
    gl_lds16(gA + k0 + 32, &sm[2048 + tid * 8]);
    #pragma unroll
    for (int w = 0; w < 3; w++) {
      gl_lds16(gB[w] + k0,      &sm[4096 + w * 4096 + tid * 8]);
      gl_lds16(gB[w] + k0 + 32, &sm[4096 + w * 4096 + 2048 + tid * 8]);
    }
    __syncthreads();
    Frag af[2][2];
    #pragma unroll
    for (int kc = 0; kc < 2; kc++)
      #pragma unroll
      for (int mi = 0; mi < 2; mi++)
        af[kc][mi].v = *(const bf16x8*)&sm[kc * 2048 + (wr + mi * 16 + l15) * 32 + quad * 8];
    #pragma unroll
    for (int w = 0; w < 3; w++)
      #pragma unroll
      for (int kc = 0; kc < 2; kc++)
        #pragma unroll
        for (int ni = 0; ni < 2; ni++) {
          Frag bf;
          bf.v = *(const bf16x8*)&sm[4096 + w * 4096 + kc * 2048 + (wc + ni * 16 + l15) * 32 + quad * 8];
          #pragma unroll
          for (int mi = 0; mi < 2; mi++)
            acc[w][mi][ni] = __builtin_amdgcn_mfma_f32_16x16x32_bf16(
                af[kc][mi].v, bf.v, acc[w][mi][ni], 0, 0, 0);
        }
    __syncthreads();
  }

  #pragma unroll
  for (int w = 0; w < 2; w++) {
    unsigned short* ob = w ? kb : qb;
    #pragma unroll
    for (int mi = 0; mi < 2; mi++)
      #pragma unroll
      for (int ni = 0; ni < 2; ni++)
        #pragma unroll
        for (int rg = 0; rg < 4; rg++) {
          int gr = m0 + wr + mi * 16 + quad * 4 + rg;
          int gc = n0 + wc + ni * 16 + l15;
          ob[(size_t)gr * Dm + gc] = f2bf(acc[w][mi][ni][rg]);
        }
  }
  #pragma unroll
  for (int mi = 0; mi < 2; mi++)
    #pragma unroll
    for (int ni = 0; ni < 2; ni++)
      #pragma unroll
      for (int rg = 0; rg < 4; rg++) {
        int rl = wr + mi * 16 + quad * 4 + rg;
        int cl = wc + ni * 16 + l15;
        sm[cl * 72 + rl] = f2bf(acc[2][mi][ni][rg]);
      }
  __syncthreads();
  {
    int d = tid >> 2, c0 = (tid & 3) * 16;
    int b_ = m0 >> 10, keybase = m0 & 1023;
    unsigned short* dst = vbt + ((size_t)((blockIdx.x * 4 + b_) * 64 + d)) * 1024 + keybase + c0;
    #pragma unroll
    for (int i = 0; i < 16; i += 4)
      *(ushort4*)(dst + i) = *(const ushort4*)&sm[d * 72 + c0 + i];
  }
}

// =============== MFMA bf16 GEMM, 64x64 tile, BK=64 (modes 1..3) ===============
template<int MODE>
__global__ void __launch_bounds__(256) gemm64(
    const unsigned short* __restrict__ Abf,
    const unsigned short* __restrict__ BT,
    unsigned short* __restrict__ o0,
    float* __restrict__ outF,
    const float* __restrict__ residF,
    const float* __restrict__ biasF,
    const float* __restrict__ hn,
    const float* __restrict__ cn,
    const float* __restrict__ flags)
{
  __shared__ unsigned short Asm[2][2048];
  __shared__ unsigned short Bsm[2][2048];
  int tid = threadIdx.x;
  int m0 = blockIdx.y * 64, n0 = blockIdx.x * 64;

  if (MODE >= 2) {
    float hmin = flags[0];
    float cmax = flags[1];
    float a = sqrtf(hmin), bq = sqrtf(cmax);
    bool allz = (a > bq) && ((a - bq) * (a - bq) > 300.0f);
    if (allz) return;   // MODE 2: Km==0 unread; MODE 3: out written by ln2 fused path
  }

  int lane = tid & 63, wave = tid >> 6;
  int quad = lane >> 4, l15 = lane & 15;
  int wr = (wave >> 1) << 5, wc = (wave & 1) << 5;

  f32x4 acc[2][2];
  #pragma unroll
  for (int i = 0; i < 2; i++)
    #pragma unroll
    for (int j = 0; j < 2; j++) acc[i][j] = (f32x4){0.f, 0.f, 0.f, 0.f};

  const unsigned short* gA = Abf + (size_t)(m0 + (tid >> 2)) * Dm + ((tid & 3) << 3);
  const unsigned short* gB = BT  + (size_t)(n0 + (tid >> 2)) * Dm + ((tid & 3) << 3);

  union Frag { bf16x8 v; ushort4 h[2]; };

  for (int k0 = 0; k0 < Dm; k0 += 64) {
    gl_lds16(gA + k0,      &Asm[0][tid * 8]);
    gl_lds16(gA + k0 + 32, &Asm[1][tid * 8]);
    gl_lds16(gB + k0,      &Bsm[0][tid * 8]);
    gl_lds16(gB + k0 + 32, &Bsm[1][tid * 8]);
    __syncthreads();
    #pragma unroll
    for (int kc = 0; kc < 2; kc++) {
      Frag af[2], bfb[2];
      #pragma unroll
      for (int i = 0; i < 2; i++) {
        af[i].v  = *(const bf16x8*)&Asm[kc][(wr + i * 16 + l15) * 32 + quad * 8];
        bfb[i].v = *(const bf16x8*)&Bsm[kc][(wc + i * 16 + l15) * 32 + quad * 8];
      }
      #pragma unroll
      for (int mi = 0; mi < 2; mi++)
        #pragma unroll
        for (int ni = 0; ni < 2; ni++)
          acc[mi][ni] = __builtin_amdgcn_mfma_f32_16x16x32_bf16(
              af[mi].v, bfb[ni].v, acc[mi][ni], 0, 0, 0);
    }
    __syncthreads();
  }

  #pragma unroll
  for (int mi = 0; mi < 2; mi++)
    #pragma unroll
    for (int ni = 0; ni < 2; ni++)
      #pragma unroll
      for (int rg = 0; rg < 4; rg++) {
        int gr = m0 + wr + mi * 16 + quad * 4 + rg;
        int gc = n0 + wc + ni * 16 + l15;
        size_t idx = (size_t)gr * Dm + gc;
        float v = acc[mi][ni][rg];
        if (MODE == 2) {
          float sq = fmaxf(hn[gr] + cn[gc] - 2.0f * v, 0.f);
          o0[idx] = f2bf(__expf(-0.5f * sq));
        } else {
          outF[idx] = residF[idx] + v + biasF[gc];
        }
      }
}

// =============== flash attention v7: swapped-QK^T softmax (S^T fragments) ===============
// mfma(K,Q) instead of mfma(Q,K): operand registers byte-identical (both frags are
// row-major rows), only arg order swaps. Lane then holds, per ni, 4 CONTIGUOUS keys of
// ONE q-row (q = wave*16+l15) -> P-pack = 8 v_cvt_pk_bf16_f32 + 4 ds_write_b64
// (replaces 48 VALU f2bf + 16 scalar ds_write_u16). PV step, ap read, O fragments and
// store identical to v6 (P lands in the same [64][72] layout). lsum: scalar/lane +
// 6 shfls per block. Same dot products, same mfma order, cvt_pk RNE == manual RNE
// -> output matches v6 to sub-ulp (lsum reorder only).
__global__ void __launch_bounds__(256) attn_flash(
    const unsigned short* __restrict__ q,
    const unsigned short* __restrict__ k,
    const unsigned short* __restrict__ vbt,
    unsigned short* __restrict__ ctx)
{
  int bx = blockIdx.x;
  int qt = (bx & 1) ? (15 - (bx >> 1)) : (bx >> 1);
  int h  = blockIdx.y;
  int b  = blockIdx.z;
  int tid = threadIdx.x;
  int lane = tid & 63, wave = tid >> 6;
  int quad = lane >> 4, l15 = lane & 15;

  __shared__ unsigned short Ks[2][2][2048];   // [buf][kc]
  __shared__ unsigned short Vt[2][2][2048];
  __shared__ unsigned short QP[4608];         // Q staging, then P[64][72] scratch

  size_t baseQK = (size_t)(b * Ls) * Dm + h * HD;
  const unsigned short* gVt = vbt + (size_t)((h * 4 + b) * 64 + (tid >> 2)) * 1024 + ((tid & 3) << 3);

  {
    const unsigned short* gQ = q + baseQK + (size_t)(qt * 64 + (tid >> 2)) * Dm + ((tid & 3) << 3);
    gl_lds16(gQ,      &QP[tid * 8]);
    gl_lds16(gQ + 32, &QP[2048 + tid * 8]);
  }
  __syncthreads();

  union Frag { bf16x8 v; ushort4 h[2]; };
  Frag afq[2];
  #pragma unroll
  for (int kc = 0; kc < 2; kc++)
    afq[kc].v = *(const bf16x8*)&QP[kc * 2048 + (wave * 16 + l15) * 32 + quad * 8];
  asm volatile("s_waitcnt lgkmcnt(0)" ::: "memory");   // QP reused as P scratch below

  f32x4 O[4];
  #pragma unroll
  for (int nj = 0; nj < 4; nj++) O[nj] = (f32x4){0.f, 0.f, 0.f, 0.f};
  float lsum1 = 0.f;    // all 16 p's per tile belong to q = wave*16+l15

  const unsigned short* gK = k + baseQK + (size_t)(tid >> 2) * Dm + ((tid & 3) << 3);

  gl_lds16(gK,      &Ks[0][0][tid * 8]);
  gl_lds16(gK + 32, &Ks[0][1][tid * 8]);
  gl_lds16(gVt,      &Vt[0][0][tid * 8]);
  gl_lds16(gVt + 32, &Vt[0][1][tid * 8]);

  for (int kt = 0; kt <= qt; kt++) {
    int cur = kt & 1;
    asm volatile("s_waitcnt lgkmcnt(0)" ::: "memory");
    __builtin_amdgcn_s_barrier();
    if (kt < qt) {
      int nxt = cur ^ 1;
      gl_lds16(gK + (size_t)((kt + 1) * 64) * Dm,      &Ks[nxt][0][tid * 8]);
      gl_lds16(gK + (size_t)((kt + 1) * 64) * Dm + 32, &Ks[nxt][1][tid * 8]);
      gl_lds16(gVt + (kt + 1) * 64,      &Vt[nxt][0][tid * 8]);
      gl_lds16(gVt + (kt + 1) * 64 + 32, &Vt[nxt][1][tid * 8]);
      asm volatile("s_waitcnt vmcnt(4)" ::: "memory");
    } else {
      asm volatile("s_waitcnt vmcnt(0)" ::: "memory");
    }
    __builtin_amdgcn_s_barrier();
    __builtin_amdgcn_sched_barrier(0);

    // S^T: sacc[ni] holds S^T[key = ni*16+quad*4+rg][q = wave*16+l15]
    f32x4 sacc[4];
    #pragma unroll
    for (int ni = 0; ni < 4; ni++) {
      sacc[ni] = (f32x4){0.f, 0.f, 0.f, 0.f};
      #pragma unroll
      for (int kc = 0; kc < 2; kc++) {
        Frag bk;
        bk.v = *(const bf16x8*)&Ks[cur][kc][(ni * 16 + l15) * 32 + quad * 8];
        sacc[ni] = __builtin_amdgcn_mfma_f32_16x16x32_bf16(bk.v, afq[kc].v, sacc[ni], 0, 0, 0);
      }
    }

    if (kt == qt) {   // causal: mask keys > q
      #pragma unroll
      for (int ni = 0; ni < 4; ni++)
        #pragma unroll
        for (int rg = 0; rg < 4; rg++)
          if (ni * 16 + quad * 4 + rg > wave * 16 + l15) sacc[ni][rg] = -1e30f;
    }

    // softmax + pack: P[q][key] with 4 contiguous keys per ni -> 1 ds_write_b64 each
    unsigned short (*Ps)[72] = (unsigned short(*)[72])QP;
    #pragma unroll
    for (int ni = 0; ni < 4; ni++) {
      float p0 = __expf(sacc[ni][0] * 0.125f);
      float p1 = __expf(sacc[ni][1] * 0.125f);
      float p2 = __expf(sacc[ni][2] * 0.125f);
      float p3 = __expf(sacc[ni][3] * 0.125f);
      lsum1 += (p0 + p1) + (p2 + p3);
      unsigned int dw0, dw1;
      asm("v_cvt_pk_bf16_f32 %0, %1, %2" : "=v"(dw0) : "v"(p0), "v"(p1));
      asm("v_cvt_pk_bf16_f32 %0, %1, %2" : "=v"(dw1) : "v"(p2), "v"(p3));
      uint2 dq; dq.x = dw0; dq.y = dw1;
      *(uint2*)&Ps[wave * 16 + l15][ni * 16 + quad * 4] = dq;
    }
    asm volatile("s_waitcnt lgkmcnt(0)" ::: "memory");   // P writes visible to own-wave reads
    __builtin_amdgcn_sched_barrier(0);                   // rule #18: pin MFMA after the wait

    Frag ap[2];
    #pragma unroll
    for (int kc = 0; kc < 2; kc++)
      ap[kc].v = *(const bf16x8*)&Ps[wave * 16 + l15][kc * 32 + quad * 8];

    #pragma unroll
    for (int nj = 0; nj < 4; nj++)
      #pragma unroll
      for (int kc = 0; kc < 2; kc++) {
        Frag bv;
        bv.v = *(const bf16x8*)&Vt[cur][kc][(nj * 16 + l15) * 32 + quad * 8];
        O[nj] = __builtin_amdgcn_mfma_f32_16x16x32_bf16(ap[kc].v, bv.v, O[nj], 0, 0, 0);
      }
  }

  // lsum: sum across the 4 quad-lanes sharing q=l15, then fetch per-output-row value
  float lq = lsum1;
  lq += __shfl_xor(lq, 16);
  lq += __shfl_xor(lq, 32);
  float linv[4];
  #pragma unroll
  for (int rg = 0; rg < 4; rg++)
    linv[rg] = 1.0f / __shfl(lq, quad * 4 + rg, 64);   // lane (quad_p=0, l15=quad*4+rg)

  #pragma unroll
  for (int nj = 0; nj < 4; nj++)
    #pragma unroll
    for (int rg = 0; rg < 4; rg++) {
      int row = qt * 64 + wave * 16 + quad * 4 + rg;
      int col = nj * 16 + l15;
      ctx[baseQK + (size_t)row * Dm + col] = f2bf(O[nj][rg] * linv[rg]);
    }
}

extern "C" void kernel_launch(void* const* d_in, const int* in_sizes, int n_in,
                              void* d_out, int out_size, void* d_ws, size_t ws_size,
                              hipStream_t stream)
{
  const float* x      = (const float*)d_in[0];
  const float* Wq     = (const float*)d_in[1];
  const float* Wk     = (const float*)d_in[2];
  const float* Wv     = (const float*)d_in[3];
  const float* Wo     = (const float*)d_in[4];
  const float* bo     = (const float*)d_in[5];
  const float* scale1 = (const float*)d_in[6];
  const float* shift1 = (const float*)d_in[7];
  const float* scale2 = (const float*)d_in[8];
  const float* shift2 = (const float*)d_in[9];
  const float* centers= (const float*)d_in[10];
  const float* lsp    = (const float*)d_in[11];
  const float* Wf     = (const float*)d_in[12];
  const float* bfv    = (const float*)d_in[13];
  float* out = (float*)d_out;

  unsigned short* wsu = (unsigned short*)d_ws;
  unsigned short* wqT = wsu;
  unsigned short* wkT = wsu + WSZ;
  unsigned short* wvT = wsu + 2 * WSZ;
  unsigned short* woT = wsu + 3 * WSZ;
  unsigned short* wfT = wsu + 4 * WSZ;
  unsigned short* cb  = wsu + 5 * WSZ;
  unsigned short* bufA = wsu + 6 * WSZ;
  unsigned short* bufB = bufA + S;
  unsigned short* hb  = bufA;
  unsigned short* qb  = bufB;
  unsigned short* kb  = bufB + S;
  unsigned short* vbt = bufB + 2 * S;
  unsigned short* ctx = bufA;
  float* x1f          = (float*)bufB;
  unsigned short* hf  = bufB + 2 * S;
  unsigned short* Km  = bufA;
  float* hn = (float*)(bufB + 3 * S);
  float* cn = hn + ROWS;
  float* flags = cn + Dm;   // [0]=min(hn), [1]=max(cn)

  dim3 gg(Dm / 64, ROWS / 64);         // (12, 64)

  prep_kernel<<<2512, 256, 0, stream>>>(Wq, Wk, Wv, Wo, Wf, wsu,
                                        centers, lsp, cb, cn,
                                        x, scale1, shift1, hb);
  gemm_qkv<<<dim3(12, 64), 256, 0, stream>>>(hb, wqT, wkT, wvT, qb, kb, vbt);
  attn_flash<<<dim3(Ls / 64, Hh, Bb), 256, 0, stream>>>(qb, kb, vbt, ctx);
  gemm64<1><<<gg, 256, 0, stream>>>(ctx, woT, nullptr, x1f, x, bo, nullptr, nullptr, nullptr);
  ln2_kernel<<<ROWS / 4, 256, 0, stream>>>(x1f, scale2, shift2, lsp, cn, bfv, hf, hn, out);
  reduce_flags<<<1, 256, 0, stream>>>(hn, cn, flags);
  gemm64<2><<<gg, 256, 0, stream>>>(hf, cb, Km, nullptr, nullptr, nullptr, hn, cn, flags);
  gemm64<3><<<gg, 256, 0, stream>>>(Km, wfT, nullptr, out, x1f, bfv, hn, cn, flags);
}

// Round 14
// 175.544 us; speedup vs baseline: 1.1198x; 1.0052x over previous
//
#include <hip/hip_runtime.h>

#define EPS_LN 1e-5f

constexpr int Dm   = 768;
constexpr int Bb   = 4;
constexpr int Ls   = 1024;
constexpr int Hh   = 12;
constexpr int HD   = 64;
constexpr int ROWS = Bb * Ls;            // 4096
constexpr size_t S = (size_t)ROWS * Dm;  // 3,145,728
constexpr size_t WSZ = (size_t)Dm * Dm;  // 589,824

typedef __attribute__((ext_vector_type(8))) short bf16x8;
typedef __attribute__((ext_vector_type(4))) float f32x4;
typedef const __attribute__((address_space(1))) unsigned int* gas_p;
typedef __attribute__((address_space(3))) unsigned int* las_p;

__device__ __forceinline__ unsigned short f2bf(float f) {
  unsigned int u = __float_as_uint(f);
  u += 0x7fffu + ((u >> 16) & 1u);   // RNE
  return (unsigned short)(u >> 16);
}
__device__ __forceinline__ void gl_lds16(const unsigned short* g, unsigned short* l) {
  __builtin_amdgcn_global_load_lds((gas_p)g, (las_p)l, 16, 0, 0);
}

// =============== fused prep: 5 weight transposes + centers(wave-per-row) + LN1(wave-per-row) ===============
// centers branch (R14): one 64-lane wave per center row, shfl butterfly, ZERO barriers
// (was 768 blocks x 16-__syncthreads tree — same pathology R8 fixed in the LNs).
__global__ void __launch_bounds__(256) prep_kernel(
    const float* __restrict__ W0, const float* __restrict__ W1,
    const float* __restrict__ W2, const float* __restrict__ W3,
    const float* __restrict__ W4, unsigned short* __restrict__ wtBase,
    const float* __restrict__ centers, const float* __restrict__ ls,
    unsigned short* __restrict__ cb, float* __restrict__ cn,
    const float* __restrict__ x, const float* __restrict__ scale,
    const float* __restrict__ shift, unsigned short* __restrict__ hb)
{
  __shared__ float smem[64 * 65];
  int bx = blockIdx.x, t = threadIdx.x;
  if (bx < 720) {
    int w = bx / 144, rem = bx - w * 144;
    int ky = rem / 12, nx = rem - ky * 12;
    const float* W = w == 0 ? W0 : w == 1 ? W1 : w == 2 ? W2 : w == 3 ? W3 : W4;
    unsigned short* WT = wtBase + (size_t)w * WSZ;
    int k0 = ky * 64, n0 = nx * 64;
    int c = t & 63, r4 = t >> 6;
    #pragma unroll
    for (int p = 0; p < 16; p++) {
      int r = p * 4 + r4;
      smem[r * 65 + c] = W[(size_t)(k0 + r) * Dm + n0 + c];
    }
    __syncthreads();
    #pragma unroll
    for (int p = 0; p < 16; p++) {
      int r = p * 4 + r4;
      WT[(size_t)(n0 + r) * Dm + k0 + c] = f2bf(smem[c * 65 + r]);
    }
  } else if (bx < 912) {
    // centers: wave-per-row, rows (bx-720)*4 + wave, 12 elems/lane as 3x float4
    int lane = t & 63;
    int j = (bx - 720) * 4 + (t >> 6);
    size_t base = (size_t)j * Dm;
    float s = 0.f;
    #pragma unroll
    for (int jj = 0; jj < 3; jj++) {
      int k4 = 4 * (lane + 64 * jj);
      float4 cv = *(const float4*)&centers[base + k4];
      float4 lv = *(const float4*)&ls[k4];
      float4 c;
      c.x = cv.x / lv.x; c.y = cv.y / lv.y; c.z = cv.z / lv.z; c.w = cv.w / lv.w;
      ushort4 o4;
      o4.x = f2bf(c.x); o4.y = f2bf(c.y); o4.z = f2bf(c.z); o4.w = f2bf(c.w);
      *(ushort4*)&cb[base + k4] = o4;
      s += c.x*c.x + c.y*c.y + c.z*c.z + c.w*c.w;
    }
    #pragma unroll
    for (int m = 1; m < 64; m <<= 1) s += __shfl_xor(s, m);
    if (lane == 0) cn[j] = s;
  } else {
    // LN1: wave-per-row, zero barriers
    int lane = t & 63;
    int row = (bx - 912) * 4 + (t >> 6);
    size_t base = (size_t)row * Dm;
    float4 v[3];
    #pragma unroll
    for (int j = 0; j < 3; j++)
      v[j] = *(const float4*)&x[base + 4 * (lane + 64 * j)];
    float sum = 0.f;
    #pragma unroll
    for (int j = 0; j < 3; j++) sum += v[j].x + v[j].y + v[j].z + v[j].w;
    #pragma unroll
    for (int m = 1; m < 64; m <<= 1) sum += __shfl_xor(sum, m);
    float mean = sum * (1.0f / Dm);
    float4 d[3];
    float vs = 0.f;
    #pragma unroll
    for (int j = 0; j < 3; j++) {
      d[j].x = v[j].x - mean; d[j].y = v[j].y - mean;
      d[j].z = v[j].z - mean; d[j].w = v[j].w - mean;
      vs += d[j].x*d[j].x + d[j].y*d[j].y + d[j].z*d[j].z + d[j].w*d[j].w;
    }
    #pragma unroll
    for (int m = 1; m < 64; m <<= 1) vs += __shfl_xor(vs, m);
    float rstd = rsqrtf(vs * (1.0f / Dm) + EPS_LN);
    #pragma unroll
    for (int j = 0; j < 3; j++) {
      int c4 = 4 * (lane + 64 * j);
      float4 sc = *(const float4*)&scale[c4];
      float4 sh = *(const float4*)&shift[c4];
      ushort4 o4;
      o4.x = f2bf(sc.x * d[j].x * rstd + sh.x);
      o4.y = f2bf(sc.y * d[j].y * rstd + sh.y);
      o4.z = f2bf(sc.z * d[j].z * rstd + sh.z);
      o4.w = f2bf(sc.w * d[j].w * rstd + sh.w);
      *(ushort4*)&hb[base + c4] = o4;
    }
  }
}

// ---- LN2 + /ls (wave-per-row) + fused degenerate-RBF output (R12-proven) ----
__global__ void __launch_bounds__(256) ln2_kernel(
    const float* __restrict__ xin, const float* __restrict__ scale,
    const float* __restrict__ shift, const float* __restrict__ ls,
    const float* __restrict__ cn, const float* __restrict__ bias,
    unsigned short* __restrict__ o, float* __restrict__ hn,
    float* __restrict__ outF)
{
  int lane = threadIdx.x & 63;
  int row = blockIdx.x * 4 + (threadIdx.x >> 6);
  size_t base = (size_t)row * Dm;
  float4 v[3];
  #pragma unroll
  for (int j = 0; j < 3; j++)
    v[j] = *(const float4*)&xin[base + 4 * (lane + 64 * j)];
  float sum = 0.f;
  #pragma unroll
  for (int j = 0; j < 3; j++) sum += v[j].x + v[j].y + v[j].z + v[j].w;
  #pragma unroll
  for (int m = 1; m < 64; m <<= 1) sum += __shfl_xor(sum, m);
  float mean = sum * (1.0f / Dm);
  float4 d[3];
  float vs = 0.f;
  #pragma unroll
  for (int j = 0; j < 3; j++) {
    d[j].x = v[j].x - mean; d[j].y = v[j].y - mean;
    d[j].z = v[j].z - mean; d[j].w = v[j].w - mean;
    vs += d[j].x*d[j].x + d[j].y*d[j].y + d[j].z*d[j].z + d[j].w*d[j].w;
  }
  #pragma unroll
  for (int m = 1; m < 64; m <<= 1) vs += __shfl_xor(vs, m);
  float rstd = rsqrtf(vs * (1.0f / Dm) + EPS_LN);
  float hsum = 0.f;
  #pragma unroll
  for (int j = 0; j < 3; j++) {
    int c4 = 4 * (lane + 64 * j);
    float4 sc = *(const float4*)&scale[c4];
    float4 sh = *(const float4*)&shift[c4];
    float4 lv = *(const float4*)&ls[c4];
    float4 hv;
    hv.x = (sc.x * d[j].x * rstd + sh.x) / lv.x;
    hv.y = (sc.y * d[j].y * rstd + sh.y) / lv.y;
    hv.z = (sc.z * d[j].z * rstd + sh.z) / lv.z;
    hv.w = (sc.w * d[j].w * rstd + sh.w) / lv.w;
    ushort4 o4;
    o4.x = f2bf(hv.x); o4.y = f2bf(hv.y); o4.z = f2bf(hv.z); o4.w = f2bf(hv.w);
    *(ushort4*)&o[base + c4] = o4;
    hsum += hv.x*hv.x + hv.y*hv.y + hv.z*hv.z + hv.w*hv.w;
  }
  #pragma unroll
  for (int m = 1; m < 64; m <<= 1) hsum += __shfl_xor(hsum, m);
  if (lane == 0) hn[row] = hsum;

  float cm = 0.f;
  #pragma unroll
  for (int j = 0; j < 12; j++) cm = fmaxf(cm, cn[lane + 64 * j]);
  #pragma unroll
  for (int m = 1; m < 64; m <<= 1) cm = fmaxf(cm, __shfl_xor(cm, m));
  float a = sqrtf(hsum), bq = sqrtf(cm);
  if ((a > bq) && ((a - bq) * (a - bq) > 300.0f)) {
    #pragma unroll
    for (int j = 0; j < 3; j++) {
      int c4 = 4 * (lane + 64 * j);
      float4 xv = v[j];
      float4 bv = *(const float4*)&bias[c4];
      float4 ov;
      ov.x = xv.x + bv.x; ov.y = xv.y + bv.y; ov.z = xv.z + bv.z; ov.w = xv.w + bv.w;
      *(float4*)&outF[base + c4] = ov;
    }
  }
}

// ---- 1-block reduce: flags[0]=min(hn), flags[1]=max(cn) (order-independent) ----
__global__ void __launch_bounds__(256) reduce_flags(
    const float* __restrict__ hn, const float* __restrict__ cn,
    float* __restrict__ flags)
{
  __shared__ float r2[256];
  int t = threadIdx.x;
  float mn = 1e30f;
  for (int i = t; i < ROWS; i += 256) mn = fminf(mn, hn[i]);
  r2[t] = mn; __syncthreads();
  for (int o = 128; o > 0; o >>= 1) { if (t < o) r2[t] = fminf(r2[t], r2[t + o]); __syncthreads(); }
  if (t == 0) flags[0] = r2[0];
  __syncthreads();
  float mx = 0.f;
  for (int i = t; i < Dm; i += 256) mx = fmaxf(mx, cn[i]);
  r2[t] = mx; __syncthreads();
  for (int o = 128; o > 0; o >>= 1) { if (t < o) r2[t] = fmaxf(r2[t], r2[t + o]); __syncthreads(); }
  if (t == 0) flags[1] = r2[0];
}

// =============== QKV 3-in-1 GEMM (R0-proven) + Q pre-scaled by 0.125 ===============
// bf16(0.125*q) == 0.125*bf16(q) exactly (power-of-2 scale commutes with RNE; no
// under/overflow at these magnitudes), and fp32 MFMA accumulation of scaled products
// equals scaled sum exactly -> attn's sacc is bit-identical to old sacc*0.125.
__global__ void __launch_bounds__(256) gemm_qkv(
    const unsigned short* __restrict__ Abf,
    const unsigned short* __restrict__ wqT,
    const unsigned short* __restrict__ wkT,
    const unsigned short* __restrict__ wvT,
    unsigned short* __restrict__ qb,
    unsigned short* __restrict__ kb,
    unsigned short* __restrict__ vbt)
{
  int m0 = blockIdx.y * 64, n0 = blockIdx.x * 64;
  __shared__ unsigned short sm[4096 + 3 * 4096];
  int tid = threadIdx.x;
  int lane = tid & 63, wave = tid >> 6;
  int quad = lane >> 4, l15 = lane & 15;
  int wr = (wave >> 1) << 5, wc = (wave & 1) << 5;

  f32x4 acc[3][2][2];
  #pragma unroll
  for (int w = 0; w < 3; w++)
    #pragma unroll
    for (int i = 0; i < 2; i++)
      #pragma unroll
      for (int j = 0; j < 2; j++) acc[w][i][j] = (f32x4){0.f, 0.f, 0.f, 0.f};

  const unsigned short* gA = Abf + (size_t)(m0 + (tid >> 2)) * Dm + ((tid & 3) << 3);
  size_t bOff = (size_t)(n0 + (tid >> 2)) * Dm + ((tid & 3) << 3);
  const unsigned short* gB[3] = { wqT + bOff, wkT + bOff, wvT + bOff };

  union Frag { bf16x8 v; ushort4 h[2]; };

  for (int k0 = 0; k0 < Dm; k0 += 64) {
    gl_lds16(gA + k0,      &sm[tid * 8]);
    gl_lds16(gA + k0 + 32, &sm[2048 + tid * 8]);
    #pragma unroll
    for (int w = 0; w < 3; w++) {
      gl_lds16(gB[w] + k0,      &sm[4096 + w * 4096 + tid * 8]);
      gl_lds16(gB[w] + k0 + 32, &sm[4096 + w * 4096 + 2048 + tid * 8]);
    }
    __syncthreads();
    Frag af[2][2];
    #pragma unroll
    for (int kc = 0; kc < 2; kc++)
      #pragma unroll
      for (int mi = 0; mi < 2; mi++)
        af[kc][mi].v = *(const bf16x8*)&sm[kc * 2048 + (wr + mi * 16 + l15) * 32 + quad * 8];
    #pragma unroll
    for (int w = 0; w < 3; w++)
      #pragma unroll
      for (int kc = 0; kc < 2; kc++)
        #pragma unroll
        for (int ni = 0; ni < 2; ni++) {
          Frag bf;
          bf.v = *(const bf16x8*)&sm[4096 + w * 4096 + kc * 2048 + (wc + ni * 16 + l15) * 32 + quad * 8];
          #pragma unroll
          for (int mi = 0; mi < 2; mi++)
            acc[w][mi][ni] = __builtin_amdgcn_mfma_f32_16x16x32_bf16(
                af[kc][mi].v, bf.v, acc[w][mi][ni], 0, 0, 0);
        }
    __syncthreads();
  }

  #pragma unroll
  for (int w = 0; w < 2; w++) {
    unsigned short* ob = w ? kb : qb;
    float scl = w ? 1.0f : 0.125f;     // Q pre-scale (exact)
    #pragma unroll
    for (int mi = 0; mi < 2; mi++)
      #pragma unroll
      for (int ni = 0; ni < 2; ni++)
        #pragma unroll
        for (int rg = 0; rg < 4; rg++) {
          int gr = m0 + wr + mi * 16 + quad * 4 + rg;
          int gc = n0 + wc + ni * 16 + l15;
          ob[(size_t)gr * Dm + gc] = f2bf(acc[w][mi][ni][rg] * scl);
        }
  }
  #pragma unroll
  for (int mi = 0; mi < 2; mi++)
    #pragma unroll
    for (int ni = 0; ni < 2; ni++)
      #pragma unroll
      for (int rg = 0; rg < 4; rg++) {
        int rl = wr + mi * 16 + quad * 4 + rg;
        int cl = wc + ni * 16 + l15;
        sm[cl * 72 + rl] = f2bf(acc[2][mi][ni][rg]);
      }
  __syncthreads();
  {
    int d = tid >> 2, c0 = (tid & 3) * 16;
    int b_ = m0 >> 10, keybase = m0 & 1023;
    unsigned short* dst = vbt + ((size_t)((blockIdx.x * 4 + b_) * 64 + d)) * 1024 + keybase + c0;
    #pragma unroll
    for (int i = 0; i < 16; i += 4)
      *(ushort4*)(dst + i) = *(const ushort4*)&sm[d * 72 + c0 + i];
  }
}

// =============== MFMA bf16 GEMM, 64x64 tile, BK=64 (modes 1..3) ===============
template<int MODE>
__global__ void __launch_bounds__(256) gemm64(
    const unsigned short* __restrict__ Abf,
    const unsigned short* __restrict__ BT,
    unsigned short* __restrict__ o0,
    float* __restrict__ outF,
    const float* __restrict__ residF,
    const float* __restrict__ biasF,
    const float* __restrict__ hn,
    const float* __restrict__ cn,
    const float* __restrict__ flags)
{
  __shared__ unsigned short Asm[2][2048];
  __shared__ unsigned short Bsm[2][2048];
  int tid = threadIdx.x;
  int m0 = blockIdx.y * 64, n0 = blockIdx.x * 64;

  if (MODE >= 2) {
    float hmin = flags[0];
    float cmax = flags[1];
    float a = sqrtf(hmin), bq = sqrtf(cmax);
    bool allz = (a > bq) && ((a - bq) * (a - bq) > 300.0f);
    if (allz) return;   // MODE 2: Km==0 unread; MODE 3: out written by ln2 fused path
  }

  int lane = tid & 63, wave = tid >> 6;
  int quad = lane >> 4, l15 = lane & 15;
  int wr = (wave >> 1) << 5, wc = (wave & 1) << 5;

  f32x4 acc[2][2];
  #pragma unroll
  for (int i = 0; i < 2; i++)
    #pragma unroll
    for (int j = 0; j < 2; j++) acc[i][j] = (f32x4){0.f, 0.f, 0.f, 0.f};

  const unsigned short* gA = Abf + (size_t)(m0 + (tid >> 2)) * Dm + ((tid & 3) << 3);
  const unsigned short* gB = BT  + (size_t)(n0 + (tid >> 2)) * Dm + ((tid & 3) << 3);

  union Frag { bf16x8 v; ushort4 h[2]; };

  for (int k0 = 0; k0 < Dm; k0 += 64) {
    gl_lds16(gA + k0,      &Asm[0][tid * 8]);
    gl_lds16(gA + k0 + 32, &Asm[1][tid * 8]);
    gl_lds16(gB + k0,      &Bsm[0][tid * 8]);
    gl_lds16(gB + k0 + 32, &Bsm[1][tid * 8]);
    __syncthreads();
    #pragma unroll
    for (int kc = 0; kc < 2; kc++) {
      Frag af[2], bfb[2];
      #pragma unroll
      for (int i = 0; i < 2; i++) {
        af[i].v  = *(const bf16x8*)&Asm[kc][(wr + i * 16 + l15) * 32 + quad * 8];
        bfb[i].v = *(const bf16x8*)&Bsm[kc][(wc + i * 16 + l15) * 32 + quad * 8];
      }
      #pragma unroll
      for (int mi = 0; mi < 2; mi++)
        #pragma unroll
        for (int ni = 0; ni < 2; ni++)
          acc[mi][ni] = __builtin_amdgcn_mfma_f32_16x16x32_bf16(
              af[mi].v, bfb[ni].v, acc[mi][ni], 0, 0, 0);
    }
    __syncthreads();
  }

  #pragma unroll
  for (int mi = 0; mi < 2; mi++)
    #pragma unroll
    for (int ni = 0; ni < 2; ni++)
      #pragma unroll
      for (int rg = 0; rg < 4; rg++) {
        int gr = m0 + wr + mi * 16 + quad * 4 + rg;
        int gc = n0 + wc + ni * 16 + l15;
        size_t idx = (size_t)gr * Dm + gc;
        float v = acc[mi][ni][rg];
        if (MODE == 2) {
          float sq = fmaxf(hn[gr] + cn[gc] - 2.0f * v, 0.f);
          o0[idx] = f2bf(__expf(-0.5f * sq));
        } else {
          outF[idx] = residF[idx] + v + biasF[gc];
        }
      }
}

// =============== flash attention v7.1: swapped-QK^T softmax, pre-scaled Q ===============
// Q arrives pre-scaled by 0.125 (exact) -> sacc needs no scale; masked -1e30 still
// exps to +0. Otherwise identical to R13's v7.
__global__ void __launch_bounds__(256) attn_flash(
    const unsigned short* __restrict__ q,
    const unsigned short* __restrict__ k,
    const unsigned short* __restrict__ vbt,
    unsigned short* __restrict__ ctx)
{
  int bx = blockIdx.x;
  int qt = (bx & 1) ? (15 - (bx >> 1)) : (bx >> 1);
  int h  = blockIdx.y;
  int b  = blockIdx.z;
  int tid = threadIdx.x;
  int lane = tid & 63, wave = tid >> 6;
  int quad = lane >> 4, l15 = lane & 15;

  __shared__ unsigned short Ks[2][2][2048];   // [buf][kc]
  __shared__ unsigned short Vt[2][2][2048];
  __shared__ unsigned short QP[4608];         // Q staging, then P[64][72] scratch

  size_t baseQK = (size_t)(b * Ls) * Dm + h * HD;
  const unsigned short* gVt = vbt + (size_t)((h * 4 + b) * 64 + (tid >> 2)) * 1024 + ((tid & 3) << 3);

  {
    const unsigned short* gQ = q + baseQK + (size_t)(qt * 64 + (tid >> 2)) * Dm + ((tid & 3) << 3);
    gl_lds16(gQ,      &QP[tid * 8]);
    gl_lds16(gQ + 32, &QP[2048 + tid * 8]);
  }
  __syncthreads();

  union Frag { bf16x8 v; ushort4 h[2]; };
  Frag afq[2];
  #pragma unroll
  for (int kc = 0; kc < 2; kc++)
    afq[kc].v = *(const bf16x8*)&QP[kc * 2048 + (wave * 16 + l15) * 32 + quad * 8];
  asm volatile("s_waitcnt lgkmcnt(0)" ::: "memory");   // QP reused as P scratch below

  f32x4 O[4];
  #pragma unroll
  for (int nj = 0; nj < 4; nj++) O[nj] = (f32x4){0.f, 0.f, 0.f, 0.f};
  float lsum1 = 0.f;    // all 16 p's per tile belong to q = wave*16+l15

  const unsigned short* gK = k + baseQK + (size_t)(tid >> 2) * Dm + ((tid & 3) << 3);

  gl_lds16(gK,      &Ks[0][0][tid * 8]);
  gl_lds16(gK + 32, &Ks[0][1][tid * 8]);
  gl_lds16(gVt,      &Vt[0][0][tid * 8]);
  gl_lds16(gVt + 32, &Vt[0][1][tid * 8]);

  for (int kt = 0; kt <= qt; kt++) {
    int cur = kt & 1;
    asm volatile("s_waitcnt lgkmcnt(0)" ::: "memory");
    __builtin_amdgcn_s_barrier();
    if (kt < qt) {
      int nxt = cur ^ 1;
      gl_lds16(gK + (size_t)((kt + 1) * 64) * Dm,      &Ks[nxt][0][tid * 8]);
      gl_lds16(gK + (size_t)((kt + 1) * 64) * Dm + 32, &Ks[nxt][1][tid * 8]);
      gl_lds16(gVt + (kt + 1) * 64,      &Vt[nxt][0][tid * 8]);
      gl_lds16(gVt + (kt + 1) * 64 + 32, &Vt[nxt][1][tid * 8]);
      asm volatile("s_waitcnt vmcnt(4)" ::: "memory");
    } else {
      asm volatile("s_waitcnt vmcnt(0)" ::: "memory");
    }
    __builtin_amdgcn_s_barrier();
    __builtin_amdgcn_sched_barrier(0);

    // S^T: sacc[ni] holds S^T[key = ni*16+quad*4+rg][q = wave*16+l15] (already /8)
    f32x4 sacc[4];
    #pragma unroll
    for (int ni = 0; ni < 4; ni++) {
      sacc[ni] = (f32x4){0.f, 0.f, 0.f, 0.f};
      #pragma unroll
      for (int kc = 0; kc < 2; kc++) {
        Frag bk;
        bk.v = *(const bf16x8*)&Ks[cur][kc][(ni * 16 + l15) * 32 + quad * 8];
        sacc[ni] = __builtin_amdgcn_mfma_f32_16x16x32_bf16(bk.v, afq[kc].v, sacc[ni], 0, 0, 0);
      }
    }

    if (kt == qt) {   // causal: mask keys > q
      #pragma unroll
      for (int ni = 0; ni < 4; ni++)
        #pragma unroll
        for (int rg = 0; rg < 4; rg++)
          if (ni * 16 + quad * 4 + rg > wave * 16 + l15) sacc[ni][rg] = -1e30f;
    }

    // softmax + pack: P[q][key] with 4 contiguous keys per ni -> 1 ds_write_b64 each
    unsigned short (*Ps)[72] = (unsigned short(*)[72])QP;
    #pragma unroll
    for (int ni = 0; ni < 4; ni++) {
      float p0 = __expf(sacc[ni][0]);
      float p1 = __expf(sacc[ni][1]);
      float p2 = __expf(sacc[ni][2]);
      float p3 = __expf(sacc[ni][3]);
      lsum1 += (p0 + p1) + (p2 + p3);
      unsigned int dw0, dw1;
      asm("v_cvt_pk_bf16_f32 %0, %1, %2" : "=v"(dw0) : "v"(p0), "v"(p1));
      asm("v_cvt_pk_bf16_f32 %0, %1, %2" : "=v"(dw1) : "v"(p2), "v"(p3));
      uint2 dq; dq.x = dw0; dq.y = dw1;
      *(uint2*)&Ps[wave * 16 + l15][ni * 16 + quad * 4] = dq;
    }
    asm volatile("s_waitcnt lgkmcnt(0)" ::: "memory");   // P writes visible to own-wave reads
    __builtin_amdgcn_sched_barrier(0);                   // rule #18: pin MFMA after the wait

    Frag ap[2];
    #pragma unroll
    for (int kc = 0; kc < 2; kc++)
      ap[kc].v = *(const bf16x8*)&Ps[wave * 16 + l15][kc * 32 + quad * 8];

    #pragma unroll
    for (int nj = 0; nj < 4; nj++)
      #pragma unroll
      for (int kc = 0; kc < 2; kc++) {
        Frag bv;
        bv.v = *(const bf16x8*)&Vt[cur][kc][(nj * 16 + l15) * 32 + quad * 8];
        O[nj] = __builtin_amdgcn_mfma_f32_16x16x32_bf16(ap[kc].v, bv.v, O[nj], 0, 0, 0);
      }
  }

  // lsum: sum across the 4 quad-lanes sharing q=l15, then fetch per-output-row value
  float lq = lsum1;
  lq += __shfl_xor(lq, 16);
  lq += __shfl_xor(lq, 32);
  float linv[4];
  #pragma unroll
  for (int rg = 0; rg < 4; rg++)
    linv[rg] = 1.0f / __shfl(lq, quad * 4 + rg, 64);   // lane (quad_p=0, l15=quad*4+rg)

  #pragma unroll
  for (int nj = 0; nj < 4; nj++)
    #pragma unroll
    for (int rg = 0; rg < 4; rg++) {
      int row = qt * 64 + wave * 16 + quad * 4 + rg;
      int col = nj * 16 + l15;
      ctx[baseQK + (size_t)row * Dm + col] = f2bf(O[nj][rg] * linv[rg]);
    }
}

extern "C" void kernel_launch(void* const* d_in, const int* in_sizes, int n_in,
                              void* d_out, int out_size, void* d_ws, size_t ws_size,
                              hipStream_t stream)
{
  const float* x      = (const float*)d_in[0];
  const float* Wq     = (const float*)d_in[1];
  const float* Wk     = (const float*)d_in[2];
  const float* Wv     = (const float*)d_in[3];
  const float* Wo     = (const float*)d_in[4];
  const float* bo     = (const float*)d_in[5];
  const float* scale1 = (const float*)d_in[6];
  const float* shift1 = (const float*)d_in[7];
  const float* scale2 = (const float*)d_in[8];
  const float* shift2 = (const float*)d_in[9];
  const float* centers= (const float*)d_in[10];
  const float* lsp    = (const float*)d_in[11];
  const float* Wf     = (const float*)d_in[12];
  const float* bfv    = (const float*)d_in[13];
  float* out = (float*)d_out;

  unsigned short* wsu = (unsigned short*)d_ws;
  unsigned short* wqT = wsu;
  unsigned short* wkT = wsu + WSZ;
  unsigned short* wvT = wsu + 2 * WSZ;
  unsigned short* woT = wsu + 3 * WSZ;
  unsigned short* wfT = wsu + 4 * WSZ;
  unsigned short* cb  = wsu + 5 * WSZ;
  unsigned short* bufA = wsu + 6 * WSZ;
  unsigned short* bufB = bufA + S;
  unsigned short* hb  = bufA;
  unsigned short* qb  = bufB;
  unsigned short* kb  = bufB + S;
  unsigned short* vbt = bufB + 2 * S;
  unsigned short* ctx = bufA;
  float* x1f          = (float*)bufB;
  unsigned short* hf  = bufB + 2 * S;
  unsigned short* Km  = bufA;
  float* hn = (float*)(bufB + 3 * S);
  float* cn = hn + ROWS;
  float* flags = cn + Dm;   // [0]=min(hn), [1]=max(cn)

  dim3 gg(Dm / 64, ROWS / 64);         // (12, 64)

  // prep grid: 720 transpose + 192 centers(wave-per-row) + 1024 LN1 = 1936
  prep_kernel<<<1936, 256, 0, stream>>>(Wq, Wk, Wv, Wo, Wf, wsu,
                                        centers, lsp, cb, cn,
                                        x, scale1, shift1, hb);
  gemm_qkv<<<dim3(12, 64), 256, 0, stream>>>(hb, wqT, wkT, wvT, qb, kb, vbt);
  attn_flash<<<dim3(Ls / 64, Hh, Bb), 256, 0, stream>>>(qb, kb, vbt, ctx);
  gemm64<1><<<gg, 256, 0, stream>>>(ctx, woT, nullptr, x1f, x, bo, nullptr, nullptr, nullptr);
  ln2_kernel<<<ROWS / 4, 256, 0, stream>>>(x1f, scale2, shift2, lsp, cn, bfv, hf, hn, out);
  reduce_flags<<<1, 256, 0, stream>>>(hn, cn, flags);
  gemm64<2><<<gg, 256, 0, stream>>>(hf, cb, Km, nullptr, nullptr, nullptr, hn, cn, flags);
  gemm64<3><<<gg, 256, 0, stream>>>(Km, wfT, nullptr, out, x1f, bfv, hn, cn, flags);
}

// Round 15
// 170.122 us; speedup vs baseline: 1.1555x; 1.0319x over previous
//
#include <hip/hip_runtime.h>

#define EPS_LN 1e-5f

constexpr int Dm   = 768;
constexpr int Bb   = 4;
constexpr int Ls   = 1024;
constexpr int Hh   = 12;
constexpr int HD   = 64;
constexpr int ROWS = Bb * Ls;            // 4096
constexpr size_t S = (size_t)ROWS * Dm;  // 3,145,728
constexpr size_t WSZ = (size_t)Dm * Dm;  // 589,824

typedef __attribute__((ext_vector_type(8))) short bf16x8;
typedef __attribute__((ext_vector_type(4))) float f32x4;
typedef const __attribute__((address_space(1))) unsigned int* gas_p;
typedef __attribute__((address_space(3))) unsigned int* las_p;

__device__ __forceinline__ unsigned short f2bf(float f) {
  unsigned int u = __float_as_uint(f);
  u += 0x7fffu + ((u >> 16) & 1u);   // RNE
  return (unsigned short)(u >> 16);
}
__device__ __forceinline__ void gl_lds16(const unsigned short* g, unsigned short* l) {
  __builtin_amdgcn_global_load_lds((gas_p)g, (las_p)l, 16, 0, 0);
}

// =============== fused prep: 5 weight transposes + centers(wave-per-row) + LN1(wave-per-row) ===============
__global__ void __launch_bounds__(256) prep_kernel(
    const float* __restrict__ W0, const float* __restrict__ W1,
    const float* __restrict__ W2, const float* __restrict__ W3,
    const float* __restrict__ W4, unsigned short* __restrict__ wtBase,
    const float* __restrict__ centers, const float* __restrict__ ls,
    unsigned short* __restrict__ cb, float* __restrict__ cn,
    const float* __restrict__ x, const float* __restrict__ scale,
    const float* __restrict__ shift, unsigned short* __restrict__ hb)
{
  __shared__ float smem[64 * 65];
  int bx = blockIdx.x, t = threadIdx.x;
  if (bx < 720) {
    int w = bx / 144, rem = bx - w * 144;
    int ky = rem / 12, nx = rem - ky * 12;
    const float* W = w == 0 ? W0 : w == 1 ? W1 : w == 2 ? W2 : w == 3 ? W3 : W4;
    unsigned short* WT = wtBase + (size_t)w * WSZ;
    int k0 = ky * 64, n0 = nx * 64;
    int c = t & 63, r4 = t >> 6;
    #pragma unroll
    for (int p = 0; p < 16; p++) {
      int r = p * 4 + r4;
      smem[r * 65 + c] = W[(size_t)(k0 + r) * Dm + n0 + c];
    }
    __syncthreads();
    #pragma unroll
    for (int p = 0; p < 16; p++) {
      int r = p * 4 + r4;
      WT[(size_t)(n0 + r) * Dm + k0 + c] = f2bf(smem[c * 65 + r]);
    }
  } else if (bx < 912) {
    // centers: wave-per-row, zero barriers
    int lane = t & 63;
    int j = (bx - 720) * 4 + (t >> 6);
    size_t base = (size_t)j * Dm;
    float s = 0.f;
    #pragma unroll
    for (int jj = 0; jj < 3; jj++) {
      int k4 = 4 * (lane + 64 * jj);
      float4 cv = *(const float4*)&centers[base + k4];
      float4 lv = *(const float4*)&ls[k4];
      float4 c;
      c.x = cv.x / lv.x; c.y = cv.y / lv.y; c.z = cv.z / lv.z; c.w = cv.w / lv.w;
      ushort4 o4;
      o4.x = f2bf(c.x); o4.y = f2bf(c.y); o4.z = f2bf(c.z); o4.w = f2bf(c.w);
      *(ushort4*)&cb[base + k4] = o4;
      s += c.x*c.x + c.y*c.y + c.z*c.z + c.w*c.w;
    }
    #pragma unroll
    for (int m = 1; m < 64; m <<= 1) s += __shfl_xor(s, m);
    if (lane == 0) cn[j] = s;
  } else {
    // LN1: wave-per-row, zero barriers
    int lane = t & 63;
    int row = (bx - 912) * 4 + (t >> 6);
    size_t base = (size_t)row * Dm;
    float4 v[3];
    #pragma unroll
    for (int j = 0; j < 3; j++)
      v[j] = *(const float4*)&x[base + 4 * (lane + 64 * j)];
    float sum = 0.f;
    #pragma unroll
    for (int j = 0; j < 3; j++) sum += v[j].x + v[j].y + v[j].z + v[j].w;
    #pragma unroll
    for (int m = 1; m < 64; m <<= 1) sum += __shfl_xor(sum, m);
    float mean = sum * (1.0f / Dm);
    float4 d[3];
    float vs = 0.f;
    #pragma unroll
    for (int j = 0; j < 3; j++) {
      d[j].x = v[j].x - mean; d[j].y = v[j].y - mean;
      d[j].z = v[j].z - mean; d[j].w = v[j].w - mean;
      vs += d[j].x*d[j].x + d[j].y*d[j].y + d[j].z*d[j].z + d[j].w*d[j].w;
    }
    #pragma unroll
    for (int m = 1; m < 64; m <<= 1) vs += __shfl_xor(vs, m);
    float rstd = rsqrtf(vs * (1.0f / Dm) + EPS_LN);
    #pragma unroll
    for (int j = 0; j < 3; j++) {
      int c4 = 4 * (lane + 64 * j);
      float4 sc = *(const float4*)&scale[c4];
      float4 sh = *(const float4*)&shift[c4];
      ushort4 o4;
      o4.x = f2bf(sc.x * d[j].x * rstd + sh.x);
      o4.y = f2bf(sc.y * d[j].y * rstd + sh.y);
      o4.z = f2bf(sc.z * d[j].z * rstd + sh.z);
      o4.w = f2bf(sc.w * d[j].w * rstd + sh.w);
      *(ushort4*)&hb[base + c4] = o4;
    }
  }
}

// ---- LN2 + /ls (wave-per-row) + fused degenerate-RBF output (R12-proven) ----
__global__ void __launch_bounds__(256) ln2_kernel(
    const float* __restrict__ xin, const float* __restrict__ scale,
    const float* __restrict__ shift, const float* __restrict__ ls,
    const float* __restrict__ cn, const float* __restrict__ bias,
    unsigned short* __restrict__ o, float* __restrict__ hn,
    float* __restrict__ outF)
{
  int lane = threadIdx.x & 63;
  int row = blockIdx.x * 4 + (threadIdx.x >> 6);
  size_t base = (size_t)row * Dm;
  float4 v[3];
  #pragma unroll
  for (int j = 0; j < 3; j++)
    v[j] = *(const float4*)&xin[base + 4 * (lane + 64 * j)];
  float sum = 0.f;
  #pragma unroll
  for (int j = 0; j < 3; j++) sum += v[j].x + v[j].y + v[j].z + v[j].w;
  #pragma unroll
  for (int m = 1; m < 64; m <<= 1) sum += __shfl_xor(sum, m);
  float mean = sum * (1.0f / Dm);
  float4 d[3];
  float vs = 0.f;
  #pragma unroll
  for (int j = 0; j < 3; j++) {
    d[j].x = v[j].x - mean; d[j].y = v[j].y - mean;
    d[j].z = v[j].z - mean; d[j].w = v[j].w - mean;
    vs += d[j].x*d[j].x + d[j].y*d[j].y + d[j].z*d[j].z + d[j].w*d[j].w;
  }
  #pragma unroll
  for (int m = 1; m < 64; m <<= 1) vs += __shfl_xor(vs, m);
  float rstd = rsqrtf(vs * (1.0f / Dm) + EPS_LN);
  float hsum = 0.f;
  #pragma unroll
  for (int j = 0; j < 3; j++) {
    int c4 = 4 * (lane + 64 * j);
    float4 sc = *(const float4*)&scale[c4];
    float4 sh = *(const float4*)&shift[c4];
    float4 lv = *(const float4*)&ls[c4];
    float4 hv;
    hv.x = (sc.x * d[j].x * rstd + sh.x) / lv.x;
    hv.y = (sc.y * d[j].y * rstd + sh.y) / lv.y;
    hv.z = (sc.z * d[j].z * rstd + sh.z) / lv.z;
    hv.w = (sc.w * d[j].w * rstd + sh.w) / lv.w;
    ushort4 o4;
    o4.x = f2bf(hv.x); o4.y = f2bf(hv.y); o4.z = f2bf(hv.z); o4.w = f2bf(hv.w);
    *(ushort4*)&o[base + c4] = o4;
    hsum += hv.x*hv.x + hv.y*hv.y + hv.z*hv.z + hv.w*hv.w;
  }
  #pragma unroll
  for (int m = 1; m < 64; m <<= 1) hsum += __shfl_xor(hsum, m);
  if (lane == 0) hn[row] = hsum;

  float cm = 0.f;
  #pragma unroll
  for (int j = 0; j < 12; j++) cm = fmaxf(cm, cn[lane + 64 * j]);
  #pragma unroll
  for (int m = 1; m < 64; m <<= 1) cm = fmaxf(cm, __shfl_xor(cm, m));
  float a = sqrtf(hsum), bq = sqrtf(cm);
  if ((a > bq) && ((a - bq) * (a - bq) > 300.0f)) {
    #pragma unroll
    for (int j = 0; j < 3; j++) {
      int c4 = 4 * (lane + 64 * j);
      float4 xv = v[j];
      float4 bv = *(const float4*)&bias[c4];
      float4 ov;
      ov.x = xv.x + bv.x; ov.y = xv.y + bv.y; ov.z = xv.z + bv.z; ov.w = xv.w + bv.w;
      *(float4*)&outF[base + c4] = ov;
    }
  }
}

// ---- 1-block reduce: flags[0]=min(hn), flags[1]=max(cn) (order-independent) ----
__global__ void __launch_bounds__(256) reduce_flags(
    const float* __restrict__ hn, const float* __restrict__ cn,
    float* __restrict__ flags)
{
  __shared__ float r2[256];
  int t = threadIdx.x;
  float mn = 1e30f;
  for (int i = t; i < ROWS; i += 256) mn = fminf(mn, hn[i]);
  r2[t] = mn; __syncthreads();
  for (int o = 128; o > 0; o >>= 1) { if (t < o) r2[t] = fminf(r2[t], r2[t + o]); __syncthreads(); }
  if (t == 0) flags[0] = r2[0];
  __syncthreads();
  float mx = 0.f;
  for (int i = t; i < Dm; i += 256) mx = fmaxf(mx, cn[i]);
  r2[t] = mx; __syncthreads();
  for (int o = 128; o > 0; o >>= 1) { if (t < o) r2[t] = fmaxf(r2[t], r2[t + o]); __syncthreads(); }
  if (t == 0) flags[1] = r2[0];
}

// =============== QKV 3-in-1 GEMM (R0-proven) + Q pre-scaled by 0.125 (exact) ===============
__global__ void __launch_bounds__(256) gemm_qkv(
    const unsigned short* __restrict__ Abf,
    const unsigned short* __restrict__ wqT,
    const unsigned short* __restrict__ wkT,
    const unsigned short* __restrict__ wvT,
    unsigned short* __restrict__ qb,
    unsigned short* __restrict__ kb,
    unsigned short* __restrict__ vbt)
{
  int m0 = blockIdx.y * 64, n0 = blockIdx.x * 64;
  __shared__ unsigned short sm[4096 + 3 * 4096];
  int tid = threadIdx.x;
  int lane = tid & 63, wave = tid >> 6;
  int quad = lane >> 4, l15 = lane & 15;
  int wr = (wave >> 1) << 5, wc = (wave & 1) << 5;

  f32x4 acc[3][2][2];
  #pragma unroll
  for (int w = 0; w < 3; w++)
    #pragma unroll
    for (int i = 0; i < 2; i++)
      #pragma unroll
      for (int j = 0; j < 2; j++) acc[w][i][j] = (f32x4){0.f, 0.f, 0.f, 0.f};

  const unsigned short* gA = Abf + (size_t)(m0 + (tid >> 2)) * Dm + ((tid & 3) << 3);
  size_t bOff = (size_t)(n0 + (tid >> 2)) * Dm + ((tid & 3) << 3);
  const unsigned short* gB[3] = { wqT + bOff, wkT + bOff, wvT + bOff };

  union Frag { bf16x8 v; ushort4 h[2]; };

  for (int k0 = 0; k0 < Dm; k0 += 64) {
    gl_lds16(gA + k0,      &sm[tid * 8]);
    gl_lds16(gA + k0 + 32, &sm[2048 + tid * 8]);
    #pragma unroll
    for (int w = 0; w < 3; w++) {
      gl_lds16(gB[w] + k0,      &sm[4096 + w * 4096 + tid * 8]);
      gl_lds16(gB[w] + k0 + 32, &sm[4096 + w * 4096 + 2048 + tid * 8]);
    }
    __syncthreads();
    Frag af[2][2];
    #pragma unroll
    for (int kc = 0; kc < 2; kc++)
      #pragma unroll
      for (int mi = 0; mi < 2; mi++)
        af[kc][mi].v = *(const bf16x8*)&sm[kc * 2048 + (wr + mi * 16 + l15) * 32 + quad * 8];
    #pragma unroll
    for (int w = 0; w < 3; w++)
      #pragma unroll
      for (int kc = 0; kc < 2; kc++)
        #pragma unroll
        for (int ni = 0; ni < 2; ni++) {
          Frag bf;
          bf.v = *(const bf16x8*)&sm[4096 + w * 4096 + kc * 2048 + (wc + ni * 16 + l15) * 32 + quad * 8];
          #pragma unroll
          for (int mi = 0; mi < 2; mi++)
            acc[w][mi][ni] = __builtin_amdgcn_mfma_f32_16x16x32_bf16(
                af[kc][mi].v, bf.v, acc[w][mi][ni], 0, 0, 0);
        }
    __syncthreads();
  }

  #pragma unroll
  for (int w = 0; w < 2; w++) {
    unsigned short* ob = w ? kb : qb;
    float scl = w ? 1.0f : 0.125f;     // Q pre-scale (exact)
    #pragma unroll
    for (int mi = 0; mi < 2; mi++)
      #pragma unroll
      for (int ni = 0; ni < 2; ni++)
        #pragma unroll
        for (int rg = 0; rg < 4; rg++) {
          int gr = m0 + wr + mi * 16 + quad * 4 + rg;
          int gc = n0 + wc + ni * 16 + l15;
          ob[(size_t)gr * Dm + gc] = f2bf(acc[w][mi][ni][rg] * scl);
        }
  }
  #pragma unroll
  for (int mi = 0; mi < 2; mi++)
    #pragma unroll
    for (int ni = 0; ni < 2; ni++)
      #pragma unroll
      for (int rg = 0; rg < 4; rg++) {
        int rl = wr + mi * 16 + quad * 4 + rg;
        int cl = wc + ni * 16 + l15;
        sm[cl * 72 + rl] = f2bf(acc[2][mi][ni][rg]);
      }
  __syncthreads();
  {
    int d = tid >> 2, c0 = (tid & 3) * 16;
    int b_ = m0 >> 10, keybase = m0 & 1023;
    unsigned short* dst = vbt + ((size_t)((blockIdx.x * 4 + b_) * 64 + d)) * 1024 + keybase + c0;
    #pragma unroll
    for (int i = 0; i < 16; i += 4)
      *(ushort4*)(dst + i) = *(const ushort4*)&sm[d * 72 + c0 + i];
  }
}

// =============== MFMA bf16 GEMM, 64x64 tile, BK=64 (modes 1..3) ===============
template<int MODE>
__global__ void __launch_bounds__(256) gemm64(
    const unsigned short* __restrict__ Abf,
    const unsigned short* __restrict__ BT,
    unsigned short* __restrict__ o0,
    float* __restrict__ outF,
    const float* __restrict__ residF,
    const float* __restrict__ biasF,
    const float* __restrict__ hn,
    const float* __restrict__ cn,
    const float* __restrict__ flags)
{
  __shared__ unsigned short Asm[2][2048];
  __shared__ unsigned short Bsm[2][2048];
  int tid = threadIdx.x;
  int m0 = blockIdx.y * 64, n0 = blockIdx.x * 64;

  if (MODE >= 2) {
    float hmin = flags[0];
    float cmax = flags[1];
    float a = sqrtf(hmin), bq = sqrtf(cmax);
    bool allz = (a > bq) && ((a - bq) * (a - bq) > 300.0f);
    if (allz) return;   // MODE 2: Km==0 unread; MODE 3: out written by ln2 fused path
  }

  int lane = tid & 63, wave = tid >> 6;
  int quad = lane >> 4, l15 = lane & 15;
  int wr = (wave >> 1) << 5, wc = (wave & 1) << 5;

  f32x4 acc[2][2];
  #pragma unroll
  for (int i = 0; i < 2; i++)
    #pragma unroll
    for (int j = 0; j < 2; j++) acc[i][j] = (f32x4){0.f, 0.f, 0.f, 0.f};

  const unsigned short* gA = Abf + (size_t)(m0 + (tid >> 2)) * Dm + ((tid & 3) << 3);
  const unsigned short* gB = BT  + (size_t)(n0 + (tid >> 2)) * Dm + ((tid & 3) << 3);

  union Frag { bf16x8 v; ushort4 h[2]; };

  for (int k0 = 0; k0 < Dm; k0 += 64) {
    gl_lds16(gA + k0,      &Asm[0][tid * 8]);
    gl_lds16(gA + k0 + 32, &Asm[1][tid * 8]);
    gl_lds16(gB + k0,      &Bsm[0][tid * 8]);
    gl_lds16(gB + k0 + 32, &Bsm[1][tid * 8]);
    __syncthreads();
    #pragma unroll
    for (int kc = 0; kc < 2; kc++) {
      Frag af[2], bfb[2];
      #pragma unroll
      for (int i = 0; i < 2; i++) {
        af[i].v  = *(const bf16x8*)&Asm[kc][(wr + i * 16 + l15) * 32 + quad * 8];
        bfb[i].v = *(const bf16x8*)&Bsm[kc][(wc + i * 16 + l15) * 32 + quad * 8];
      }
      #pragma unroll
      for (int mi = 0; mi < 2; mi++)
        #pragma unroll
        for (int ni = 0; ni < 2; ni++)
          acc[mi][ni] = __builtin_amdgcn_mfma_f32_16x16x32_bf16(
              af[mi].v, bfb[ni].v, acc[mi][ni], 0, 0, 0);
    }
    __syncthreads();
  }

  #pragma unroll
  for (int mi = 0; mi < 2; mi++)
    #pragma unroll
    for (int ni = 0; ni < 2; ni++)
      #pragma unroll
      for (int rg = 0; rg < 4; rg++) {
        int gr = m0 + wr + mi * 16 + quad * 4 + rg;
        int gc = n0 + wc + ni * 16 + l15;
        size_t idx = (size_t)gr * Dm + gc;
        float v = acc[mi][ni][rg];
        if (MODE == 2) {
          float sq = fmaxf(hn[gr] + cn[gc] - 2.0f * v, 0.f);
          o0[idx] = f2bf(__expf(-0.5f * sq));
        } else {
          outF[idx] = residF[idx] + v + biasF[gc];
        }
      }
}

// =============== flash attention v7.2: CU-load-balanced qt assignment ===============
// Co-residency analysis: 768 blocks / 256 CUs, linear id = bx + 16*(h+12*b); blocks
// {i, i+256, i+512} co-resident under round-robin dispatch share bx (256 % 16 == 0)
// -> same qt -> worst CU does 3x16=48 tile-iters vs 25.5 avg (~1.9x imbalance).
// Fix: slot s = (h+12b)>>4 in {0,1,2} selects one of 3 bijective qt-permutations
// P0(v)=v, P1, P2 with P0(v)+P1(v)+P2(v) == 22+(v&1) -> every CU gets 25/26 iters.
// Within a slot, consecutive v still alternates low/high (zigzag preserved) -> no
// regression under consecutive-block mapping. Pure block reorder: bit-identical output.
__global__ void __launch_bounds__(256) attn_flash(
    const unsigned short* __restrict__ q,
    const unsigned short* __restrict__ k,
    const unsigned short* __restrict__ vbt,
    unsigned short* __restrict__ ctx)
{
  int bx = blockIdx.x;
  int h  = blockIdx.y;
  int b  = blockIdx.z;
  int v  = (bx & 1) ? (15 - (bx >> 1)) : (bx >> 1);   // zigzag base
  int s  = (h + 12 * b) >> 4;                          // co-residency slot 0/1/2
  int qt;
  if (s == 0)      qt = v;
  else if (s == 1) qt = (v & 1) ? (15 - (v >> 1)) : (7 - (v >> 1));
  else             qt = (v & 1) ? (7  - (v >> 1)) : (15 - (v >> 1));

  int tid = threadIdx.x;
  int lane = tid & 63, wave = tid >> 6;
  int quad = lane >> 4, l15 = lane & 15;

  __shared__ unsigned short Ks[2][2][2048];   // [buf][kc]
  __shared__ unsigned short Vt[2][2][2048];
  __shared__ unsigned short QP[4608];         // Q staging, then P[64][72] scratch

  size_t baseQK = (size_t)(b * Ls) * Dm + h * HD;
  const unsigned short* gVt = vbt + (size_t)((h * 4 + b) * 64 + (tid >> 2)) * 1024 + ((tid & 3) << 3);

  {
    const unsigned short* gQ = q + baseQK + (size_t)(qt * 64 + (tid >> 2)) * Dm + ((tid & 3) << 3);
    gl_lds16(gQ,      &QP[tid * 8]);
    gl_lds16(gQ + 32, &QP[2048 + tid * 8]);
  }
  __syncthreads();

  union Frag { bf16x8 v; ushort4 h[2]; };
  Frag afq[2];
  #pragma unroll
  for (int kc = 0; kc < 2; kc++)
    afq[kc].v = *(const bf16x8*)&QP[kc * 2048 + (wave * 16 + l15) * 32 + quad * 8];
  asm volatile("s_waitcnt lgkmcnt(0)" ::: "memory");   // QP reused as P scratch below

  f32x4 O[4];
  #pragma unroll
  for (int nj = 0; nj < 4; nj++) O[nj] = (f32x4){0.f, 0.f, 0.f, 0.f};
  float lsum1 = 0.f;    // all 16 p's per tile belong to q = wave*16+l15

  const unsigned short* gK = k + baseQK + (size_t)(tid >> 2) * Dm + ((tid & 3) << 3);

  gl_lds16(gK,      &Ks[0][0][tid * 8]);
  gl_lds16(gK + 32, &Ks[0][1][tid * 8]);
  gl_lds16(gVt,      &Vt[0][0][tid * 8]);
  gl_lds16(gVt + 32, &Vt[0][1][tid * 8]);

  for (int kt = 0; kt <= qt; kt++) {
    int cur = kt & 1;
    asm volatile("s_waitcnt lgkmcnt(0)" ::: "memory");
    __builtin_amdgcn_s_barrier();
    if (kt < qt) {
      int nxt = cur ^ 1;
      gl_lds16(gK + (size_t)((kt + 1) * 64) * Dm,      &Ks[nxt][0][tid * 8]);
      gl_lds16(gK + (size_t)((kt + 1) * 64) * Dm + 32, &Ks[nxt][1][tid * 8]);
      gl_lds16(gVt + (kt + 1) * 64,      &Vt[nxt][0][tid * 8]);
      gl_lds16(gVt + (kt + 1) * 64 + 32, &Vt[nxt][1][tid * 8]);
      asm volatile("s_waitcnt vmcnt(4)" ::: "memory");
    } else {
      asm volatile("s_waitcnt vmcnt(0)" ::: "memory");
    }
    __builtin_amdgcn_s_barrier();
    __builtin_amdgcn_sched_barrier(0);

    // S^T: sacc[ni] holds S^T[key = ni*16+quad*4+rg][q = wave*16+l15] (already /8)
    f32x4 sacc[4];
    #pragma unroll
    for (int ni = 0; ni < 4; ni++) {
      sacc[ni] = (f32x4){0.f, 0.f, 0.f, 0.f};
      #pragma unroll
      for (int kc = 0; kc < 2; kc++) {
        Frag bk;
        bk.v = *(const bf16x8*)&Ks[cur][kc][(ni * 16 + l15) * 32 + quad * 8];
        sacc[ni] = __builtin_amdgcn_mfma_f32_16x16x32_bf16(bk.v, afq[kc].v, sacc[ni], 0, 0, 0);
      }
    }

    if (kt == qt) {   // causal: mask keys > q
      #pragma unroll
      for (int ni = 0; ni < 4; ni++)
        #pragma unroll
        for (int rg = 0; rg < 4; rg++)
          if (ni * 16 + quad * 4 + rg > wave * 16 + l15) sacc[ni][rg] = -1e30f;
    }

    // softmax + pack: P[q][key] with 4 contiguous keys per ni -> 1 ds_write_b64 each
    unsigned short (*Ps)[72] = (unsigned short(*)[72])QP;
    #pragma unroll
    for (int ni = 0; ni < 4; ni++) {
      float p0 = __expf(sacc[ni][0]);
      float p1 = __expf(sacc[ni][1]);
      float p2 = __expf(sacc[ni][2]);
      float p3 = __expf(sacc[ni][3]);
      lsum1 += (p0 + p1) + (p2 + p3);
      unsigned int dw0, dw1;
      asm("v_cvt_pk_bf16_f32 %0, %1, %2" : "=v"(dw0) : "v"(p0), "v"(p1));
      asm("v_cvt_pk_bf16_f32 %0, %1, %2" : "=v"(dw1) : "v"(p2), "v"(p3));
      uint2 dq; dq.x = dw0; dq.y = dw1;
      *(uint2*)&Ps[wave * 16 + l15][ni * 16 + quad * 4] = dq;
    }
    asm volatile("s_waitcnt lgkmcnt(0)" ::: "memory");   // P writes visible to own-wave reads
    __builtin_amdgcn_sched_barrier(0);                   // rule #18: pin MFMA after the wait

    Frag ap[2];
    #pragma unroll
    for (int kc = 0; kc < 2; kc++)
      ap[kc].v = *(const bf16x8*)&Ps[wave * 16 + l15][kc * 32 + quad * 8];

    #pragma unroll
    for (int nj = 0; nj < 4; nj++)
      #pragma unroll
      for (int kc = 0; kc < 2; kc++) {
        Frag bv;
        bv.v = *(const bf16x8*)&Vt[cur][kc][(nj * 16 + l15) * 32 + quad * 8];
        O[nj] = __builtin_amdgcn_mfma_f32_16x16x32_bf16(ap[kc].v, bv.v, O[nj], 0, 0, 0);
      }
  }

  // lsum: sum across the 4 quad-lanes sharing q=l15, then fetch per-output-row value
  float lq = lsum1;
  lq += __shfl_xor(lq, 16);
  lq += __shfl_xor(lq, 32);
  float linv[4];
  #pragma unroll
  for (int rg = 0; rg < 4; rg++)
    linv[rg] = 1.0f / __shfl(lq, quad * 4 + rg, 64);   // lane (quad_p=0, l15=quad*4+rg)

  #pragma unroll
  for (int nj = 0; nj < 4; nj++)
    #pragma unroll
    for (int rg = 0; rg < 4; rg++) {
      int row = qt * 64 + wave * 16 + quad * 4 + rg;
      int col = nj * 16 + l15;
      ctx[baseQK + (size_t)row * Dm + col] = f2bf(O[nj][rg] * linv[rg]);
    }
}

extern "C" void kernel_launch(void* const* d_in, const int* in_sizes, int n_in,
                              void* d_out, int out_size, void* d_ws, size_t ws_size,
                              hipStream_t stream)
{
  const float* x      = (const float*)d_in[0];
  const float* Wq     = (const float*)d_in[1];
  const float* Wk     = (const float*)d_in[2];
  const float* Wv     = (const float*)d_in[3];
  const float* Wo     = (const float*)d_in[4];
  const float* bo     = (const float*)d_in[5];
  const float* scale1 = (const float*)d_in[6];
  const float* shift1 = (const float*)d_in[7];
  const float* scale2 = (const float*)d_in[8];
  const float* shift2 = (const float*)d_in[9];
  const float* centers= (const float*)d_in[10];
  const float* lsp    = (const float*)d_in[11];
  const float* Wf     = (const float*)d_in[12];
  const float* bfv    = (const float*)d_in[13];
  float* out = (float*)d_out;

  unsigned short* wsu = (unsigned short*)d_ws;
  unsigned short* wqT = wsu;
  unsigned short* wkT = wsu + WSZ;
  unsigned short* wvT = wsu + 2 * WSZ;
  unsigned short* woT = wsu + 3 * WSZ;
  unsigned short* wfT = wsu + 4 * WSZ;
  unsigned short* cb  = wsu + 5 * WSZ;
  unsigned short* bufA = wsu + 6 * WSZ;
  unsigned short* bufB = bufA + S;
  unsigned short* hb  = bufA;
  unsigned short* qb  = bufB;
  unsigned short* kb  = bufB + S;
  unsigned short* vbt = bufB + 2 * S;
  unsigned short* ctx = bufA;
  float* x1f          = (float*)bufB;
  unsigned short* hf  = bufB + 2 * S;
  unsigned short* Km  = bufA;
  float* hn = (float*)(bufB + 3 * S);
  float* cn = hn + ROWS;
  float* flags = cn + Dm;   // [0]=min(hn), [1]=max(cn)

  dim3 gg(Dm / 64, ROWS / 64);         // (12, 64)

  // prep grid: 720 transpose + 192 centers(wave-per-row) + 1024 LN1 = 1936
  prep_kernel<<<1936, 256, 0, stream>>>(Wq, Wk, Wv, Wo, Wf, wsu,
                                        centers, lsp, cb, cn,
                                        x, scale1, shift1, hb);
  gemm_qkv<<<dim3(12, 64), 256, 0, stream>>>(hb, wqT, wkT, wvT, qb, kb, vbt);
  attn_flash<<<dim3(Ls / 64, Hh, Bb), 256, 0, stream>>>(qb, kb, vbt, ctx);
  gemm64<1><<<gg, 256, 0, stream>>>(ctx, woT, nullptr, x1f, x, bo, nullptr, nullptr, nullptr);
  ln2_kernel<<<ROWS / 4, 256, 0, stream>>>(x1f, scale2, shift2, lsp, cn, bfv, hf, hn, out);
  reduce_flags<<<1, 256, 0, stream>>>(hn, cn, flags);
  gemm64<2><<<gg, 256, 0, stream>>>(hf, cb, Km, nullptr, nullptr, nullptr, hn, cn, flags);
  gemm64<3><<<gg, 256, 0, stream>>>(Km, wfT, nullptr, out, x1f, bfv, hn, cn, flags);
}

// Round 16
// 166.283 us; speedup vs baseline: 1.1822x; 1.0231x over previous
//
#include <hip/hip_runtime.h>

#define EPS_LN 1e-5f

constexpr int Dm   = 768;
constexpr int Bb   = 4;
constexpr int Ls   = 1024;
constexpr int Hh   = 12;
constexpr int HD   = 64;
constexpr int ROWS = Bb * Ls;            // 4096
constexpr size_t S = (size_t)ROWS * Dm;  // 3,145,728
constexpr size_t WSZ = (size_t)Dm * Dm;  // 589,824

typedef __attribute__((ext_vector_type(8))) short bf16x8;
typedef __attribute__((ext_vector_type(4))) float f32x4;
typedef const __attribute__((address_space(1))) unsigned int* gas_p;
typedef __attribute__((address_space(3))) unsigned int* las_p;

__device__ __forceinline__ unsigned short f2bf(float f) {
  unsigned int u = __float_as_uint(f);
  u += 0x7fffu + ((u >> 16) & 1u);   // RNE
  return (unsigned short)(u >> 16);
}
__device__ __forceinline__ void gl_lds16(const unsigned short* g, unsigned short* l) {
  __builtin_amdgcn_global_load_lds((gas_p)g, (las_p)l, 16, 0, 0);
}

// =============== fused prep: 5 weight transposes + centers(wave-per-row) + LN1(wave-per-row) ===============
__global__ void __launch_bounds__(256) prep_kernel(
    const float* __restrict__ W0, const float* __restrict__ W1,
    const float* __restrict__ W2, const float* __restrict__ W3,
    const float* __restrict__ W4, unsigned short* __restrict__ wtBase,
    const float* __restrict__ centers, const float* __restrict__ ls,
    unsigned short* __restrict__ cb, float* __restrict__ cn,
    const float* __restrict__ x, const float* __restrict__ scale,
    const float* __restrict__ shift, unsigned short* __restrict__ hb)
{
  __shared__ float smem[64 * 65];
  int bx = blockIdx.x, t = threadIdx.x;
  if (bx < 720) {
    int w = bx / 144, rem = bx - w * 144;
    int ky = rem / 12, nx = rem - ky * 12;
    const float* W = w == 0 ? W0 : w == 1 ? W1 : w == 2 ? W2 : w == 3 ? W3 : W4;
    unsigned short* WT = wtBase + (size_t)w * WSZ;
    int k0 = ky * 64, n0 = nx * 64;
    int c = t & 63, r4 = t >> 6;
    #pragma unroll
    for (int p = 0; p < 16; p++) {
      int r = p * 4 + r4;
      smem[r * 65 + c] = W[(size_t)(k0 + r) * Dm + n0 + c];
    }
    __syncthreads();
    #pragma unroll
    for (int p = 0; p < 16; p++) {
      int r = p * 4 + r4;
      WT[(size_t)(n0 + r) * Dm + k0 + c] = f2bf(smem[c * 65 + r]);
    }
  } else if (bx < 912) {
    // centers: wave-per-row, zero barriers
    int lane = t & 63;
    int j = (bx - 720) * 4 + (t >> 6);
    size_t base = (size_t)j * Dm;
    float s = 0.f;
    #pragma unroll
    for (int jj = 0; jj < 3; jj++) {
      int k4 = 4 * (lane + 64 * jj);
      float4 cv = *(const float4*)&centers[base + k4];
      float4 lv = *(const float4*)&ls[k4];
      float4 c;
      c.x = cv.x / lv.x; c.y = cv.y / lv.y; c.z = cv.z / lv.z; c.w = cv.w / lv.w;
      ushort4 o4;
      o4.x = f2bf(c.x); o4.y = f2bf(c.y); o4.z = f2bf(c.z); o4.w = f2bf(c.w);
      *(ushort4*)&cb[base + k4] = o4;
      s += c.x*c.x + c.y*c.y + c.z*c.z + c.w*c.w;
    }
    #pragma unroll
    for (int m = 1; m < 64; m <<= 1) s += __shfl_xor(s, m);
    if (lane == 0) cn[j] = s;
  } else {
    // LN1: wave-per-row, zero barriers
    int lane = t & 63;
    int row = (bx - 912) * 4 + (t >> 6);
    size_t base = (size_t)row * Dm;
    float4 v[3];
    #pragma unroll
    for (int j = 0; j < 3; j++)
      v[j] = *(const float4*)&x[base + 4 * (lane + 64 * j)];
    float sum = 0.f;
    #pragma unroll
    for (int j = 0; j < 3; j++) sum += v[j].x + v[j].y + v[j].z + v[j].w;
    #pragma unroll
    for (int m = 1; m < 64; m <<= 1) sum += __shfl_xor(sum, m);
    float mean = sum * (1.0f / Dm);
    float4 d[3];
    float vs = 0.f;
    #pragma unroll
    for (int j = 0; j < 3; j++) {
      d[j].x = v[j].x - mean; d[j].y = v[j].y - mean;
      d[j].z = v[j].z - mean; d[j].w = v[j].w - mean;
      vs += d[j].x*d[j].x + d[j].y*d[j].y + d[j].z*d[j].z + d[j].w*d[j].w;
    }
    #pragma unroll
    for (int m = 1; m < 64; m <<= 1) vs += __shfl_xor(vs, m);
    float rstd = rsqrtf(vs * (1.0f / Dm) + EPS_LN);
    #pragma unroll
    for (int j = 0; j < 3; j++) {
      int c4 = 4 * (lane + 64 * j);
      float4 sc = *(const float4*)&scale[c4];
      float4 sh = *(const float4*)&shift[c4];
      ushort4 o4;
      o4.x = f2bf(sc.x * d[j].x * rstd + sh.x);
      o4.y = f2bf(sc.y * d[j].y * rstd + sh.y);
      o4.z = f2bf(sc.z * d[j].z * rstd + sh.z);
      o4.w = f2bf(sc.w * d[j].w * rstd + sh.w);
      *(ushort4*)&hb[base + c4] = o4;
    }
  }
}

// ---- LN2 + /ls (wave-per-row) + fused degenerate-RBF output (R12-proven) ----
__global__ void __launch_bounds__(256) ln2_kernel(
    const float* __restrict__ xin, const float* __restrict__ scale,
    const float* __restrict__ shift, const float* __restrict__ ls,
    const float* __restrict__ cn, const float* __restrict__ bias,
    unsigned short* __restrict__ o, float* __restrict__ hn,
    float* __restrict__ outF)
{
  int lane = threadIdx.x & 63;
  int row = blockIdx.x * 4 + (threadIdx.x >> 6);
  size_t base = (size_t)row * Dm;
  float4 v[3];
  #pragma unroll
  for (int j = 0; j < 3; j++)
    v[j] = *(const float4*)&xin[base + 4 * (lane + 64 * j)];
  float sum = 0.f;
  #pragma unroll
  for (int j = 0; j < 3; j++) sum += v[j].x + v[j].y + v[j].z + v[j].w;
  #pragma unroll
  for (int m = 1; m < 64; m <<= 1) sum += __shfl_xor(sum, m);
  float mean = sum * (1.0f / Dm);
  float4 d[3];
  float vs = 0.f;
  #pragma unroll
  for (int j = 0; j < 3; j++) {
    d[j].x = v[j].x - mean; d[j].y = v[j].y - mean;
    d[j].z = v[j].z - mean; d[j].w = v[j].w - mean;
    vs += d[j].x*d[j].x + d[j].y*d[j].y + d[j].z*d[j].z + d[j].w*d[j].w;
  }
  #pragma unroll
  for (int m = 1; m < 64; m <<= 1) vs += __shfl_xor(vs, m);
  float rstd = rsqrtf(vs * (1.0f / Dm) + EPS_LN);
  float hsum = 0.f;
  #pragma unroll
  for (int j = 0; j < 3; j++) {
    int c4 = 4 * (lane + 64 * j);
    float4 sc = *(const float4*)&scale[c4];
    float4 sh = *(const float4*)&shift[c4];
    float4 lv = *(const float4*)&ls[c4];
    float4 hv;
    hv.x = (sc.x * d[j].x * rstd + sh.x) / lv.x;
    hv.y = (sc.y * d[j].y * rstd + sh.y) / lv.y;
    hv.z = (sc.z * d[j].z * rstd + sh.z) / lv.z;
    hv.w = (sc.w * d[j].w * rstd + sh.w) / lv.w;
    ushort4 o4;
    o4.x = f2bf(hv.x); o4.y = f2bf(hv.y); o4.z = f2bf(hv.z); o4.w = f2bf(hv.w);
    *(ushort4*)&o[base + c4] = o4;
    hsum += hv.x*hv.x + hv.y*hv.y + hv.z*hv.z + hv.w*hv.w;
  }
  #pragma unroll
  for (int m = 1; m < 64; m <<= 1) hsum += __shfl_xor(hsum, m);
  if (lane == 0) hn[row] = hsum;

  float cm = 0.f;
  #pragma unroll
  for (int j = 0; j < 12; j++) cm = fmaxf(cm, cn[lane + 64 * j]);
  #pragma unroll
  for (int m = 1; m < 64; m <<= 1) cm = fmaxf(cm, __shfl_xor(cm, m));
  float a = sqrtf(hsum), bq = sqrtf(cm);
  if ((a > bq) && ((a - bq) * (a - bq) > 300.0f)) {
    #pragma unroll
    for (int j = 0; j < 3; j++) {
      int c4 = 4 * (lane + 64 * j);
      float4 xv = v[j];
      float4 bv = *(const float4*)&bias[c4];
      float4 ov;
      ov.x = xv.x + bv.x; ov.y = xv.y + bv.y; ov.z = xv.z + bv.z; ov.w = xv.w + bv.w;
      *(float4*)&outF[base + c4] = ov;
    }
  }
}

// =============== QKV 3-in-1 GEMM (R0-proven) + Q pre-scaled by 0.125 (exact) ===============
__global__ void __launch_bounds__(256) gemm_qkv(
    const unsigned short* __restrict__ Abf,
    const unsigned short* __restrict__ wqT,
    const unsigned short* __restrict__ wkT,
    const unsigned short* __restrict__ wvT,
    unsigned short* __restrict__ qb,
    unsigned short* __restrict__ kb,
    unsigned short* __restrict__ vbt)
{
  int m0 = blockIdx.y * 64, n0 = blockIdx.x * 64;
  __shared__ unsigned short sm[4096 + 3 * 4096];
  int tid = threadIdx.x;
  int lane = tid & 63, wave = tid >> 6;
  int quad = lane >> 4, l15 = lane & 15;
  int wr = (wave >> 1) << 5, wc = (wave & 1) << 5;

  f32x4 acc[3][2][2];
  #pragma unroll
  for (int w = 0; w < 3; w++)
    #pragma unroll
    for (int i = 0; i < 2; i++)
      #pragma unroll
      for (int j = 0; j < 2; j++) acc[w][i][j] = (f32x4){0.f, 0.f, 0.f, 0.f};

  const unsigned short* gA = Abf + (size_t)(m0 + (tid >> 2)) * Dm + ((tid & 3) << 3);
  size_t bOff = (size_t)(n0 + (tid >> 2)) * Dm + ((tid & 3) << 3);
  const unsigned short* gB[3] = { wqT + bOff, wkT + bOff, wvT + bOff };

  union Frag { bf16x8 v; ushort4 h[2]; };

  for (int k0 = 0; k0 < Dm; k0 += 64) {
    gl_lds16(gA + k0,      &sm[tid * 8]);
    gl_lds16(gA + k0 + 32, &sm[2048 + tid * 8]);
    #pragma unroll
    for (int w = 0; w < 3; w++) {
      gl_lds16(gB[w] + k0,      &sm[4096 + w * 4096 + tid * 8]);
      gl_lds16(gB[w] + k0 + 32, &sm[4096 + w * 4096 + 2048 + tid * 8]);
    }
    __syncthreads();
    Frag af[2][2];
    #pragma unroll
    for (int kc = 0; kc < 2; kc++)
      #pragma unroll
      for (int mi = 0; mi < 2; mi++)
        af[kc][mi].v = *(const bf16x8*)&sm[kc * 2048 + (wr + mi * 16 + l15) * 32 + quad * 8];
    #pragma unroll
    for (int w = 0; w < 3; w++)
      #pragma unroll
      for (int kc = 0; kc < 2; kc++)
        #pragma unroll
        for (int ni = 0; ni < 2; ni++) {
          Frag bf;
          bf.v = *(const bf16x8*)&sm[4096 + w * 4096 + kc * 2048 + (wc + ni * 16 + l15) * 32 + quad * 8];
          #pragma unroll
          for (int mi = 0; mi < 2; mi++)
            acc[w][mi][ni] = __builtin_amdgcn_mfma_f32_16x16x32_bf16(
                af[kc][mi].v, bf.v, acc[w][mi][ni], 0, 0, 0);
        }
    __syncthreads();
  }

  #pragma unroll
  for (int w = 0; w < 2; w++) {
    unsigned short* ob = w ? kb : qb;
    float scl = w ? 1.0f : 0.125f;     // Q pre-scale (exact)
    #pragma unroll
    for (int mi = 0; mi < 2; mi++)
      #pragma unroll
      for (int ni = 0; ni < 2; ni++)
        #pragma unroll
        for (int rg = 0; rg < 4; rg++) {
          int gr = m0 + wr + mi * 16 + quad * 4 + rg;
          int gc = n0 + wc + ni * 16 + l15;
          ob[(size_t)gr * Dm + gc] = f2bf(acc[w][mi][ni][rg] * scl);
        }
  }
  #pragma unroll
  for (int mi = 0; mi < 2; mi++)
    #pragma unroll
    for (int ni = 0; ni < 2; ni++)
      #pragma unroll
      for (int rg = 0; rg < 4; rg++) {
        int rl = wr + mi * 16 + quad * 4 + rg;
        int cl = wc + ni * 16 + l15;
        sm[cl * 72 + rl] = f2bf(acc[2][mi][ni][rg]);
      }
  __syncthreads();
  {
    int d = tid >> 2, c0 = (tid & 3) * 16;
    int b_ = m0 >> 10, keybase = m0 & 1023;
    unsigned short* dst = vbt + ((size_t)((blockIdx.x * 4 + b_) * 64 + d)) * 1024 + keybase + c0;
    #pragma unroll
    for (int i = 0; i < 16; i += 4)
      *(ushort4*)(dst + i) = *(const ushort4*)&sm[d * 72 + c0 + i];
  }
}

// =============== MFMA bf16 GEMM, 64x64 tile, BK=64 (modes 1..3) ===============
// MODE>=2 degeneracy: PER-BLOCK decision, no global flags / no reduce_flags launch.
// Each wave redundantly computes cmax = max(cn[0..767]) and hminBlk = min(hn[m0..m0+63])
// (zero barriers). Block-all-degenerate <=> hminBlk degenerate (monotone in hn).
// Consistency: decision depends only on the block's 64 rows -> all gemm64<2> n-blocks
// over those rows agree -> Km[m0..63][*] fully written or fully skipped; gemm64<3>
// over the same rows uses the same test. Mixed blocks: degenerate rows' exp == 0.0
// exactly, so gemm64<3> writes resid+0+bias == ln2's fused write. Bit-identical.
template<int MODE>
__global__ void __launch_bounds__(256) gemm64(
    const unsigned short* __restrict__ Abf,
    const unsigned short* __restrict__ BT,
    unsigned short* __restrict__ o0,
    float* __restrict__ outF,
    const float* __restrict__ residF,
    const float* __restrict__ biasF,
    const float* __restrict__ hn,
    const float* __restrict__ cn)
{
  __shared__ unsigned short Asm[2][2048];
  __shared__ unsigned short Bsm[2][2048];
  int tid = threadIdx.x;
  int m0 = blockIdx.y * 64, n0 = blockIdx.x * 64;

  if (MODE >= 2) {
    int lane0 = tid & 63;
    float cm = 0.f;
    #pragma unroll
    for (int j = 0; j < 12; j++) cm = fmaxf(cm, cn[lane0 + 64 * j]);
    #pragma unroll
    for (int m = 1; m < 64; m <<= 1) cm = fmaxf(cm, __shfl_xor(cm, m));
    float hm = hn[m0 + lane0];
    #pragma unroll
    for (int m = 1; m < 64; m <<= 1) hm = fminf(hm, __shfl_xor(hm, m));
    float a = sqrtf(hm), bq = sqrtf(cm);
    bool allz = (a > bq) && ((a - bq) * (a - bq) > 300.0f);
    if (allz) return;   // MODE 2: Km rows zero & unread; MODE 3: out written by ln2
  }

  int lane = tid & 63, wave = tid >> 6;
  int quad = lane >> 4, l15 = lane & 15;
  int wr = (wave >> 1) << 5, wc = (wave & 1) << 5;

  f32x4 acc[2][2];
  #pragma unroll
  for (int i = 0; i < 2; i++)
    #pragma unroll
    for (int j = 0; j < 2; j++) acc[i][j] = (f32x4){0.f, 0.f, 0.f, 0.f};

  const unsigned short* gA = Abf + (size_t)(m0 + (tid >> 2)) * Dm + ((tid & 3) << 3);
  const unsigned short* gB = BT  + (size_t)(n0 + (tid >> 2)) * Dm + ((tid & 3) << 3);

  union Frag { bf16x8 v; ushort4 h[2]; };

  for (int k0 = 0; k0 < Dm; k0 += 64) {
    gl_lds16(gA + k0,      &Asm[0][tid * 8]);
    gl_lds16(gA + k0 + 32, &Asm[1][tid * 8]);
    gl_lds16(gB + k0,      &Bsm[0][tid * 8]);
    gl_lds16(gB + k0 + 32, &Bsm[1][tid * 8]);
    __syncthreads();
    #pragma unroll
    for (int kc = 0; kc < 2; kc++) {
      Frag af[2], bfb[2];
      #pragma unroll
      for (int i = 0; i < 2; i++) {
        af[i].v  = *(const bf16x8*)&Asm[kc][(wr + i * 16 + l15) * 32 + quad * 8];
        bfb[i].v = *(const bf16x8*)&Bsm[kc][(wc + i * 16 + l15) * 32 + quad * 8];
      }
      #pragma unroll
      for (int mi = 0; mi < 2; mi++)
        #pragma unroll
        for (int ni = 0; ni < 2; ni++)
          acc[mi][ni] = __builtin_amdgcn_mfma_f32_16x16x32_bf16(
              af[mi].v, bfb[ni].v, acc[mi][ni], 0, 0, 0);
    }
    __syncthreads();
  }

  #pragma unroll
  for (int mi = 0; mi < 2; mi++)
    #pragma unroll
    for (int ni = 0; ni < 2; ni++)
      #pragma unroll
      for (int rg = 0; rg < 4; rg++) {
        int gr = m0 + wr + mi * 16 + quad * 4 + rg;
        int gc = n0 + wc + ni * 16 + l15;
        size_t idx = (size_t)gr * Dm + gc;
        float v = acc[mi][ni][rg];
        if (MODE == 2) {
          float sq = fmaxf(hn[gr] + cn[gc] - 2.0f * v, 0.f);
          o0[idx] = f2bf(__expf(-0.5f * sq));
        } else {
          outF[idx] = residF[idx] + v + biasF[gc];
        }
      }
}

// =============== flash attention v7.2 (R15-proven): CU-load-balanced qt, swapped-QK^T ===============
__global__ void __launch_bounds__(256) attn_flash(
    const unsigned short* __restrict__ q,
    const unsigned short* __restrict__ k,
    const unsigned short* __restrict__ vbt,
    unsigned short* __restrict__ ctx)
{
  int bx = blockIdx.x;
  int h  = blockIdx.y;
  int b  = blockIdx.z;
  int v  = (bx & 1) ? (15 - (bx >> 1)) : (bx >> 1);   // zigzag base
  int s  = (h + 12 * b) >> 4;                          // co-residency slot 0/1/2
  int qt;
  if (s == 0)      qt = v;
  else if (s == 1) qt = (v & 1) ? (15 - (v >> 1)) : (7 - (v >> 1));
  else             qt = (v & 1) ? (7  - (v >> 1)) : (15 - (v >> 1));

  int tid = threadIdx.x;
  int lane = tid & 63, wave = tid >> 6;
  int quad = lane >> 4, l15 = lane & 15;

  __shared__ unsigned short Ks[2][2][2048];   // [buf][kc]
  __shared__ unsigned short Vt[2][2][2048];
  __shared__ unsigned short QP[4608];         // Q staging, then P[64][72] scratch

  size_t baseQK = (size_t)(b * Ls) * Dm + h * HD;
  const unsigned short* gVt = vbt + (size_t)((h * 4 + b) * 64 + (tid >> 2)) * 1024 + ((tid & 3) << 3);

  {
    const unsigned short* gQ = q + baseQK + (size_t)(qt * 64 + (tid >> 2)) * Dm + ((tid & 3) << 3);
    gl_lds16(gQ,      &QP[tid * 8]);
    gl_lds16(gQ + 32, &QP[2048 + tid * 8]);
  }
  __syncthreads();

  union Frag { bf16x8 v; ushort4 h[2]; };
  Frag afq[2];
  #pragma unroll
  for (int kc = 0; kc < 2; kc++)
    afq[kc].v = *(const bf16x8*)&QP[kc * 2048 + (wave * 16 + l15) * 32 + quad * 8];
  asm volatile("s_waitcnt lgkmcnt(0)" ::: "memory");   // QP reused as P scratch below

  f32x4 O[4];
  #pragma unroll
  for (int nj = 0; nj < 4; nj++) O[nj] = (f32x4){0.f, 0.f, 0.f, 0.f};
  float lsum1 = 0.f;    // all 16 p's per tile belong to q = wave*16+l15

  const unsigned short* gK = k + baseQK + (size_t)(tid >> 2) * Dm + ((tid & 3) << 3);

  gl_lds16(gK,      &Ks[0][0][tid * 8]);
  gl_lds16(gK + 32, &Ks[0][1][tid * 8]);
  gl_lds16(gVt,      &Vt[0][0][tid * 8]);
  gl_lds16(gVt + 32, &Vt[0][1][tid * 8]);

  for (int kt = 0; kt <= qt; kt++) {
    int cur = kt & 1;
    asm volatile("s_waitcnt lgkmcnt(0)" ::: "memory");
    __builtin_amdgcn_s_barrier();
    if (kt < qt) {
      int nxt = cur ^ 1;
      gl_lds16(gK + (size_t)((kt + 1) * 64) * Dm,      &Ks[nxt][0][tid * 8]);
      gl_lds16(gK + (size_t)((kt + 1) * 64) * Dm + 32, &Ks[nxt][1][tid * 8]);
      gl_lds16(gVt + (kt + 1) * 64,      &Vt[nxt][0][tid * 8]);
      gl_lds16(gVt + (kt + 1) * 64 + 32, &Vt[nxt][1][tid * 8]);
      asm volatile("s_waitcnt vmcnt(4)" ::: "memory");
    } else {
      asm volatile("s_waitcnt vmcnt(0)" ::: "memory");
    }
    __builtin_amdgcn_s_barrier();
    __builtin_amdgcn_sched_barrier(0);

    // S^T: sacc[ni] holds S^T[key = ni*16+quad*4+rg][q = wave*16+l15] (already /8)
    f32x4 sacc[4];
    #pragma unroll
    for (int ni = 0; ni < 4; ni++) {
      sacc[ni] = (f32x4){0.f, 0.f, 0.f, 0.f};
      #pragma unroll
      for (int kc = 0; kc < 2; kc++) {
        Frag bk;
        bk.v = *(const bf16x8*)&Ks[cur][kc][(ni * 16 + l15) * 32 + quad * 8];
        sacc[ni] = __builtin_amdgcn_mfma_f32_16x16x32_bf16(bk.v, afq[kc].v, sacc[ni], 0, 0, 0);
      }
    }

    if (kt == qt) {   // causal: mask keys > q
      #pragma unroll
      for (int ni = 0; ni < 4; ni++)
        #pragma unroll
        for (int rg = 0; rg < 4; rg++)
          if (ni * 16 + quad * 4 + rg > wave * 16 + l15) sacc[ni][rg] = -1e30f;
    }

    // softmax + pack: P[q][key] with 4 contiguous keys per ni -> 1 ds_write_b64 each
    unsigned short (*Ps)[72] = (unsigned short(*)[72])QP;
    #pragma unroll
    for (int ni = 0; ni < 4; ni++) {
      float p0 = __expf(sacc[ni][0]);
      float p1 = __expf(sacc[ni][1]);
      float p2 = __expf(sacc[ni][2]);
      float p3 = __expf(sacc[ni][3]);
      lsum1 += (p0 + p1) + (p2 + p3);
      unsigned int dw0, dw1;
      asm("v_cvt_pk_bf16_f32 %0, %1, %2" : "=v"(dw0) : "v"(p0), "v"(p1));
      asm("v_cvt_pk_bf16_f32 %0, %1, %2" : "=v"(dw1) : "v"(p2), "v"(p3));
      uint2 dq; dq.x = dw0; dq.y = dw1;
      *(uint2*)&Ps[wave * 16 + l15][ni * 16 + quad * 4] = dq;
    }
    asm volatile("s_waitcnt lgkmcnt(0)" ::: "memory");   // P writes visible to own-wave reads
    __builtin_amdgcn_sched_barrier(0);                   // rule #18: pin MFMA after the wait

    Frag ap[2];
    #pragma unroll
    for (int kc = 0; kc < 2; kc++)
      ap[kc].v = *(const bf16x8*)&Ps[wave * 16 + l15][kc * 32 + quad * 8];

    #pragma unroll
    for (int nj = 0; nj < 4; nj++)
      #pragma unroll
      for (int kc = 0; kc < 2; kc++) {
        Frag bv;
        bv.v = *(const bf16x8*)&Vt[cur][kc][(nj * 16 + l15) * 32 + quad * 8];
        O[nj] = __builtin_amdgcn_mfma_f32_16x16x32_bf16(ap[kc].v, bv.v, O[nj], 0, 0, 0);
      }
  }

  // lsum: sum across the 4 quad-lanes sharing q=l15, then fetch per-output-row value
  float lq = lsum1;
  lq += __shfl_xor(lq, 16);
  lq += __shfl_xor(lq, 32);
  float linv[4];
  #pragma unroll
  for (int rg = 0; rg < 4; rg++)
    linv[rg] = 1.0f / __shfl(lq, quad * 4 + rg, 64);   // lane (quad_p=0, l15=quad*4+rg)

  #pragma unroll
  for (int nj = 0; nj < 4; nj++)
    #pragma unroll
    for (int rg = 0; rg < 4; rg++) {
      int row = qt * 64 + wave * 16 + quad * 4 + rg;
      int col = nj * 16 + l15;
      ctx[baseQK + (size_t)row * Dm + col] = f2bf(O[nj][rg] * linv[rg]);
    }
}

extern "C" void kernel_launch(void* const* d_in, const int* in_sizes, int n_in,
                              void* d_out, int out_size, void* d_ws, size_t ws_size,
                              hipStream_t stream)
{
  const float* x      = (const float*)d_in[0];
  const float* Wq     = (const float*)d_in[1];
  const float* Wk     = (const float*)d_in[2];
  const float* Wv     = (const float*)d_in[3];
  const float* Wo     = (const float*)d_in[4];
  const float* bo     = (const float*)d_in[5];
  const float* scale1 = (const float*)d_in[6];
  const float* shift1 = (const float*)d_in[7];
  const float* scale2 = (const float*)d_in[8];
  const float* shift2 = (const float*)d_in[9];
  const float* centers= (const float*)d_in[10];
  const float* lsp    = (const float*)d_in[11];
  const float* Wf     = (const float*)d_in[12];
  const float* bfv    = (const float*)d_in[13];
  float* out = (float*)d_out;

  unsigned short* wsu = (unsigned short*)d_ws;
  unsigned short* wqT = wsu;
  unsigned short* wkT = wsu + WSZ;
  unsigned short* wvT = wsu + 2 * WSZ;
  unsigned short* woT = wsu + 3 * WSZ;
  unsigned short* wfT = wsu + 4 * WSZ;
  unsigned short* cb  = wsu + 5 * WSZ;
  unsigned short* bufA = wsu + 6 * WSZ;
  unsigned short* bufB = bufA + S;
  unsigned short* hb  = bufA;
  unsigned short* qb  = bufB;
  unsigned short* kb  = bufB + S;
  unsigned short* vbt = bufB + 2 * S;
  unsigned short* ctx = bufA;
  float* x1f          = (float*)bufB;
  unsigned short* hf  = bufB + 2 * S;
  unsigned short* Km  = bufA;
  float* hn = (float*)(bufB + 3 * S);
  float* cn = hn + ROWS;

  dim3 gg(Dm / 64, ROWS / 64);         // (12, 64)

  // prep grid: 720 transpose + 192 centers(wave-per-row) + 1024 LN1 = 1936
  prep_kernel<<<1936, 256, 0, stream>>>(Wq, Wk, Wv, Wo, Wf, wsu,
                                        centers, lsp, cb, cn,
                                        x, scale1, shift1, hb);
  gemm_qkv<<<dim3(12, 64), 256, 0, stream>>>(hb, wqT, wkT, wvT, qb, kb, vbt);
  attn_flash<<<dim3(Ls / 64, Hh, Bb), 256, 0, stream>>>(qb, kb, vbt, ctx);
  gemm64<1><<<gg, 256, 0, stream>>>(ctx, woT, nullptr, x1f, x, bo, nullptr, nullptr);
  ln2_kernel<<<ROWS / 4, 256, 0, stream>>>(x1f, scale2, shift2, lsp, cn, bfv, hf, hn, out);
  gemm64<2><<<gg, 256, 0, stream>>>(hf, cb, Km, nullptr, nullptr, nullptr, hn, cn);
  gemm64<3><<<gg, 256, 0, stream>>>(Km, wfT, nullptr, out, x1f, bfv, hn, cn);
}